// Round 6
// baseline (161.523 us; speedup 1.0000x reference)
//
#include <hip/hip_runtime.h>
#include <math.h>

#define NN   2048
#define KZ   20
#define IFZ  128
#define AHZ  4
#define AFZ  32
#define ROWS (NN*KZ)           // 40960
#define TWO_KZ (2*KZ)          // 40
#define NSLOT 96               // inverse-index bucket capacity (Poisson(20), P(>96)~0)

typedef __attribute__((ext_vector_type(8))) short short8v;   // 8 bf16 = 4 VGPR
typedef __attribute__((ext_vector_type(4))) float f32x4;     // MFMA acc

__device__ __forceinline__ float blo(unsigned int u) {      // low bf16 of packed pair
    union { unsigned int i; float f; } x; x.i = u << 16; return x.f;
}
__device__ __forceinline__ float bhi(unsigned int u) {      // high bf16 of packed pair
    union { unsigned int i; float f; } x; x.i = u & 0xffff0000u; return x.f;
}
__device__ __forceinline__ unsigned short f2b(float f) {
    union { float f; unsigned int i; } x; x.f = f;
    unsigned int r = x.i + 0x7fffu + ((x.i >> 16) & 1u);
    return (unsigned short)(r >> 16);
}
__device__ __forceinline__ unsigned pack2(float a, float b) {
    return (unsigned)f2b(a) | ((unsigned)f2b(b) << 16);
}

// ---------------------------------------------------------------------------
// prep_x: x (f32, ROWS x 128) -> xb (bf16). 8 elems/thread.
// ---------------------------------------------------------------------------
__global__ __launch_bounds__(256) void prep_x(const float* __restrict__ x,
                                              unsigned short* __restrict__ xb)
{
    const int gid = blockIdx.x * 256 + threadIdx.x;
    const float4* src = (const float4*)x;
    float4 v0 = src[gid * 2];
    float4 v1 = src[gid * 2 + 1];
    uint4 o;
    o.x = pack2(v0.x, v0.y);
    o.y = pack2(v0.z, v0.w);
    o.z = pack2(v1.x, v1.y);
    o.w = pack2(v1.z, v1.w);
    ((uint4*)xb)[gid] = o;
}

// ---------------------------------------------------------------------------
// wtrans: build transposed bf16 weights.
// ---------------------------------------------------------------------------
__global__ __launch_bounds__(256) void wtrans(
    const float* __restrict__ Wq, const float* __restrict__ Wk,
    const float* __restrict__ Wv, const float* __restrict__ Wg,
    const float* __restrict__ Wback,
    unsigned short* __restrict__ Wt, unsigned short* __restrict__ Wbt)
{
    const int gid = blockIdx.x * 256 + threadIdx.x;
    if (gid < 512 * 128) {
        const int n = gid >> 7, k = gid & 127;
        const float* W; int c;
        if      (n < 128) { W = Wq; c = n; }
        else if (n < 256) { W = Wk; c = n - 128; }
        else if (n < 384) { W = Wv; c = n - 256; }
        else              { W = Wg; c = n - 384; }
        Wt[gid] = f2b(W[k * 128 + c]);
    } else {
        const int g2 = gid - 512 * 128;
        const int n = g2 >> 7, k = g2 & 127;
        Wbt[g2] = f2b(Wback[k * 128 + n]);
    }
}

// ---------------------------------------------------------------------------
// bproj: b = xb @ Wb  (ROWS x 4), f32 accum from bf16 x. One row per thread.
// ---------------------------------------------------------------------------
__global__ __launch_bounds__(256) void bproj(const unsigned short* __restrict__ xb,
                                             const float* __restrict__ Wb,
                                             float* __restrict__ bbuf)
{
    const int row = blockIdx.x * 256 + threadIdx.x;
    const unsigned* xv = (const unsigned*)xb + (size_t)row * 64;
    const float4* wv = (const float4*)Wb;
    float4 acc = make_float4(0.f, 0.f, 0.f, 0.f);
    #pragma unroll
    for (int u = 0; u < 64; ++u) {
        const unsigned xu = xv[u];
        const float x0 = blo(xu), x1 = bhi(xu);
        const float4 w0 = wv[2*u], w1 = wv[2*u+1];
        acc.x += x0*w0.x + x1*w1.x;
        acc.y += x0*w0.y + x1*w1.y;
        acc.z += x0*w0.z + x1*w1.z;
        acc.w += x0*w0.w + x1*w1.w;
    }
    ((float4*)bbuf)[row] = acc;
}

// ---------------------------------------------------------------------------
// proj_gemm: [q|k|v|g] = xb @ Wt^T, MFMA 16x16x32 bf16, no LDS.
// ---------------------------------------------------------------------------
__global__ __launch_bounds__(256) void proj_gemm(
    const unsigned short* __restrict__ xb, const unsigned short* __restrict__ Wt,
    const float* __restrict__ bg,
    unsigned short* __restrict__ qb, unsigned short* __restrict__ kb,
    unsigned short* __restrict__ vb, unsigned short* __restrict__ gb)
{
    const int row0 = blockIdx.x * 128;
    const int col0 = blockIdx.y * 128;
    const int wid  = threadIdx.x >> 6;
    const int lane = threadIdx.x & 63;
    const int wm = wid >> 1, wn = wid & 1;
    const int l15 = lane & 15, lg = lane >> 4;

    f32x4 acc[4][4];
    #pragma unroll
    for (int i = 0; i < 4; ++i)
        #pragma unroll
        for (int j = 0; j < 4; ++j) acc[i][j] = (f32x4){0.f,0.f,0.f,0.f};

    const unsigned short* Ab = xb + ((size_t)(row0 + wm*64 + l15)) * IFZ + lg*8;
    const unsigned short* Bb = Wt + ((size_t)(col0 + wn*64 + l15)) * IFZ + lg*8;

    #pragma unroll
    for (int ks = 0; ks < 4; ++ks) {
        short8v a[4], b[4];
        #pragma unroll
        for (int f = 0; f < 4; ++f) {
            a[f] = *((const short8v*)(Ab + (size_t)f*16*IFZ + ks*32));
            b[f] = *((const short8v*)(Bb + (size_t)f*16*IFZ + ks*32));
        }
        #pragma unroll
        for (int fm = 0; fm < 4; ++fm)
            #pragma unroll
            for (int fn = 0; fn < 4; ++fn)
                acc[fm][fn] = __builtin_amdgcn_mfma_f32_16x16x32_bf16(
                    a[fm], b[fn], acc[fm][fn], 0, 0, 0);
    }

    unsigned short* ob;
    switch (blockIdx.y) { case 0: ob = qb; break; case 1: ob = kb; break;
                          case 2: ob = vb; break; default: ob = gb; break; }
    const bool gate = (blockIdx.y == 3);

    #pragma unroll
    for (int fm = 0; fm < 4; ++fm)
        #pragma unroll
        for (int fn = 0; fn < 4; ++fn)
            #pragma unroll
            for (int j = 0; j < 4; ++j) {
                const int row = row0 + wm*64 + fm*16 + lg*4 + j;
                const int cl  = wn*64 + fn*16 + l15;
                float v = acc[fm][fn][j];
                if (gate) v = 1.f / (1.f + __expf(-(v + bg[cl])));
                ob[(size_t)row * IFZ + cl] = f2b(v);
            }
}

// ---------------------------------------------------------------------------
// zero_cnt + build_inv: inverse edge index. bucket order is atomic-race
// dependent but every slot lands in exactly one bucket and per-slot outputs
// are order-independent -> deterministic results.
// ---------------------------------------------------------------------------
__global__ __launch_bounds__(256) void zero_cnt(int* __restrict__ cnt)
{
    const int i = blockIdx.x * 256 + threadIdx.x;
    if (i < NN) cnt[i] = 0;
}

__global__ __launch_bounds__(256) void build_inv(const int* __restrict__ edge,
                                                 int* __restrict__ cnt,
                                                 int* __restrict__ inv)
{
    const int s = blockIdx.x * 256 + threadIdx.x;   // 0..ROWS-1
    const int e = edge[s];
    const int pos = atomicAdd(&cnt[e], 1);
    if (pos < NSLOT) inv[e * NSLOT + pos] = s;
}

// ---------------------------------------------------------------------------
// sself: per node n, s_self[kk,j,a] = q.k/scale + b[n,j,a] -> ssf (f32).
// LDS layout [row][a*17+c2] (uints) -> 2-way bank aliasing only (free).
// ---------------------------------------------------------------------------
__global__ __launch_bounds__(256) void sself_kernel(
    const unsigned short* __restrict__ qb, const unsigned short* __restrict__ kb,
    const float* __restrict__ bbuf, float* __restrict__ ssf)
{
    const int n   = blockIdx.x;
    const int tid = threadIdx.x;
    __shared__ unsigned qsu[KZ*68];
    __shared__ unsigned ksu[KZ*68];
    __shared__ float    bs[KZ*AHZ];

    const unsigned* qbu = (const unsigned*)qb;
    const unsigned* kbu = (const unsigned*)kb;
    for (int i = tid; i < KZ*64; i += 256) {
        const int r = i >> 6, l = i & 63;
        const int d = r*68 + (l >> 4)*17 + (l & 15);
        qsu[d] = qbu[(size_t)n*1280 + i];
        ksu[d] = kbu[(size_t)n*1280 + i];
    }
    if (tid < KZ*AHZ) bs[tid] = bbuf[(size_t)n*(KZ*AHZ) + tid];
    __syncthreads();

    const float rscale = 0.17677669529663687f;
    for (int it = tid; it < KZ*KZ*AHZ; it += 256) {
        const int a  = it & 3;
        const int j  = (it >> 2) % KZ;
        const int kk = it / (KZ*AHZ);
        const unsigned* qp = &qsu[kk*68 + a*17];
        const unsigned* kp = &ksu[j*68 + a*17];
        float s = 0.f;
        #pragma unroll
        for (int c2 = 0; c2 < 16; ++c2) {
            const unsigned qu = qp[c2], ku = kp[c2];
            s += blo(qu)*blo(ku) + bhi(qu)*bhi(ku);
        }
        ssf[(size_t)n*1600 + kk*80 + a*20 + j] = s*rscale + bs[j*AHZ + a];
    }
}

// ---------------------------------------------------------------------------
// scatter_nb: per DESTINATION node m. K_m,V_m staged once; serves all
// incoming (n,kk) slots. Per slot (one wave each): gather q-row (256B) +
// self-score row, compute 20 nb dots, softmax over 40, ctx_nb, write
// ctx_nb (packed bf16) + w_self (packed bf16).
// ---------------------------------------------------------------------------
__global__ __launch_bounds__(256) void scatter_nb(
    const unsigned short* __restrict__ qb, const unsigned short* __restrict__ kb,
    const unsigned short* __restrict__ vb, const float* __restrict__ bbuf,
    const float* __restrict__ ssf, const int* __restrict__ cnt,
    const int* __restrict__ inv, unsigned* __restrict__ wsfu,
    unsigned* __restrict__ ctxnb)
{
    const int m   = blockIdx.x;
    const int tid = threadIdx.x;
    const int wv  = tid >> 6;
    const int lane = tid & 63;
    const int a   = lane >> 4;
    const int l16 = lane & 15;

    __shared__ unsigned ksu[KZ*68];
    __shared__ unsigned vsu[KZ*68];
    __shared__ float    bs[KZ*AHZ];
    __shared__ float    srow[4][4][44];   // [wave][head][40 scores]

    const unsigned* kbu = (const unsigned*)kb;
    const unsigned* vbu = (const unsigned*)vb;
    for (int i = tid; i < KZ*64; i += 256) {
        const int r = i >> 6, l = i & 63;
        const int d = r*68 + (l >> 4)*17 + (l & 15);
        ksu[d] = kbu[(size_t)m*1280 + i];
        vsu[d] = vbu[(size_t)m*1280 + i];
    }
    if (tid < KZ*AHZ) bs[tid] = bbuf[(size_t)m*(KZ*AHZ) + tid];
    __syncthreads();

    int count = cnt[m];
    if (count > NSLOT) count = NSLOT;
    const float rscale = 0.17677669529663687f;

    for (int i = wv; i < count; i += 4) {
        const int s = inv[m*NSLOT + i];

        // q row for this lane's head -> 32 f32 regs
        const uint4* qsrc = (const uint4*)qb + (size_t)s*16 + a*4;
        unsigned qu[16];
        {
            const uint4 q0 = qsrc[0], q1 = qsrc[1], q2 = qsrc[2], q3 = qsrc[3];
            qu[0]=q0.x; qu[1]=q0.y; qu[2]=q0.z; qu[3]=q0.w;
            qu[4]=q1.x; qu[5]=q1.y; qu[6]=q1.z; qu[7]=q1.w;
            qu[8]=q2.x; qu[9]=q2.y; qu[10]=q2.z; qu[11]=q2.w;
            qu[12]=q3.x; qu[13]=q3.y; qu[14]=q3.z; qu[15]=q3.w;
        }
        float qf[32];
        #pragma unroll
        for (int c = 0; c < 16; ++c) { qf[2*c] = blo(qu[c]); qf[2*c+1] = bhi(qu[c]); }

        // nb dot for j = l16, plus j2 = 16+l16 for l16<4; self-score loads
        {
            const unsigned* kp = &ksu[l16*68 + a*17];
            float sd = 0.f;
            #pragma unroll
            for (int c2 = 0; c2 < 16; ++c2) {
                const unsigned ku = kp[c2];
                sd += qf[2*c2]*blo(ku) + qf[2*c2+1]*bhi(ku);
            }
            srow[wv][a][20 + l16] = sd*rscale + bs[l16*AHZ + a];
            srow[wv][a][l16]      = ssf[(size_t)s*80 + a*20 + l16];
        }
        if (l16 < 4) {
            const int j2 = 16 + l16;
            const unsigned* kp = &ksu[j2*68 + a*17];
            float sd = 0.f;
            #pragma unroll
            for (int c2 = 0; c2 < 16; ++c2) {
                const unsigned ku = kp[c2];
                sd += qf[2*c2]*blo(ku) + qf[2*c2+1]*bhi(ku);
            }
            srow[wv][a][20 + j2] = sd*rscale + bs[j2*AHZ + a];
            srow[wv][a][j2]      = ssf[(size_t)s*80 + a*20 + j2];
        }
        asm volatile("s_waitcnt lgkmcnt(0)" ::: "memory");

        // softmax over 40, 16 lanes per head row
        {
            float* rp = &srow[wv][a][0];
            float v0 = rp[l16];
            float v1 = rp[l16 + 16];
            float v2 = (l16 < 8) ? rp[l16 + 32] : -1e30f;
            float mx = fmaxf(fmaxf(v0, v1), v2);
            #pragma unroll
            for (int off = 1; off < 16; off <<= 1) mx = fmaxf(mx, __shfl_xor(mx, off, 16));
            const float e0 = __expf(v0 - mx);
            const float e1 = __expf(v1 - mx);
            const float e2 = (l16 < 8) ? __expf(v2 - mx) : 0.f;
            float sm = e0 + e1 + e2;
            #pragma unroll
            for (int off = 1; off < 16; off <<= 1) sm += __shfl_xor(sm, off, 16);
            const float invs = 1.f / sm;
            rp[l16]      = e0 * invs;
            rp[l16 + 16] = e1 * invs;
            if (l16 < 8) rp[l16 + 32] = e2 * invs;
        }
        asm volatile("s_waitcnt lgkmcnt(0)" ::: "memory");

        // ctx_nb: lane (a, c2=l16) -> column pair
        {
            const float* wrow = &srow[wv][a][20];
            const unsigned* vp = &vsu[a*17 + l16];
            float acc0 = 0.f, acc1 = 0.f;
            #pragma unroll
            for (int j = 0; j < KZ; ++j) {
                const float w = wrow[j];
                const unsigned u = vp[j*68];
                acc0 += w*blo(u); acc1 += w*bhi(u);
            }
            ctxnb[(size_t)s*64 + lane] = pack2(acc0, acc1);
        }
        // w_self packed bf16: 10 uints per head
        if (l16 < 10)
            wsfu[(size_t)s*40 + a*10 + l16] =
                pack2(srow[wv][a][2*l16], srow[wv][a][2*l16 + 1]);
    }
}

// ---------------------------------------------------------------------------
// finalize: per node n: ctx = ctx_self(w_self, V_n) + ctx_nb; out = gate*ctx.
// ---------------------------------------------------------------------------
__global__ __launch_bounds__(256) void finalize_kernel(
    const unsigned short* __restrict__ vb, const unsigned short* __restrict__ gb,
    const unsigned* __restrict__ wsfu, const unsigned* __restrict__ ctxnb,
    unsigned short* __restrict__ obuf)
{
    const int n   = blockIdx.x;
    const int tid = threadIdx.x;
    const int lane = tid & 63;
    const int a   = lane >> 4;
    const int c2  = lane & 15;

    __shared__ unsigned vsu[KZ*68];
    __shared__ unsigned wsu[KZ*40];

    const unsigned* vbu = (const unsigned*)vb;
    for (int i = tid; i < KZ*64; i += 256) {
        const int r = i >> 6, l = i & 63;
        vsu[r*68 + (l >> 4)*17 + (l & 15)] = vbu[(size_t)n*1280 + i];
    }
    for (int i = tid; i < KZ*40; i += 256) wsu[i] = wsfu[(size_t)n*800 + i];
    __syncthreads();

    const unsigned* gbu = (const unsigned*)gb;
    unsigned* obu = (unsigned*)obuf;

    #pragma unroll
    for (int i = 0; i < 5; ++i) {
        const int kk = (tid >> 6) + 4*i;
        const unsigned* wrow = &wsu[kk*40 + a*10];
        const unsigned* vp = &vsu[a*17 + c2];
        float acc0 = 0.f, acc1 = 0.f;
        #pragma unroll
        for (int jp = 0; jp < 10; ++jp) {
            const unsigned wu = wrow[jp];
            const float w0 = blo(wu), w1 = bhi(wu);
            const unsigned u0 = vp[(2*jp)*68];
            const unsigned u1 = vp[(2*jp+1)*68];
            acc0 += w0*blo(u0) + w1*blo(u1);
            acc1 += w0*bhi(u0) + w1*bhi(u1);
        }
        const size_t idx = (size_t)n*1280 + kk*64 + lane;
        const unsigned cn = ctxnb[idx];
        const unsigned gu = gbu[idx];
        const float o0 = (acc0 + blo(cn)) * blo(gu);
        const float o1 = (acc1 + bhi(cn)) * bhi(gu);
        obu[idx] = pack2(o0, o1);
    }
}

// ---------------------------------------------------------------------------
// back_ln: y = ob @ Wbt^T + bback + sqrt2*x, then LayerNorm. MFMA, BM=64.
// ---------------------------------------------------------------------------
__global__ __launch_bounds__(256) void back_ln_kernel(
    const unsigned short* __restrict__ ob, const unsigned short* __restrict__ Wbt,
    const float* __restrict__ x, const float* __restrict__ bback,
    const float* __restrict__ gamma, const float* __restrict__ beta,
    float* __restrict__ out)
{
    __shared__ float ys[64][132];
    __shared__ float st[64][2];
    const int row0 = blockIdx.x * 64;
    const int tid  = threadIdx.x;
    const int wid  = tid >> 6;
    const int lane = tid & 63;
    const int wm = wid >> 1, wn = wid & 1;
    const int l15 = lane & 15, lg = lane >> 4;

    f32x4 acc[2][4];
    #pragma unroll
    for (int i = 0; i < 2; ++i)
        #pragma unroll
        for (int j = 0; j < 4; ++j) acc[i][j] = (f32x4){0.f,0.f,0.f,0.f};

    const unsigned short* Ab = ob  + ((size_t)(row0 + wm*32 + l15)) * IFZ + lg*8;
    const unsigned short* Bb = Wbt + ((size_t)(wn*64 + l15)) * IFZ + lg*8;

    #pragma unroll
    for (int ksI = 0; ksI < 4; ++ksI) {
        short8v a[2], b[4];
        #pragma unroll
        for (int f = 0; f < 2; ++f) a[f] = *((const short8v*)(Ab + (size_t)f*16*IFZ + ksI*32));
        #pragma unroll
        for (int f = 0; f < 4; ++f) b[f] = *((const short8v*)(Bb + (size_t)f*16*IFZ + ksI*32));
        #pragma unroll
        for (int fm = 0; fm < 2; ++fm)
            #pragma unroll
            for (int fn = 0; fn < 4; ++fn)
                acc[fm][fn] = __builtin_amdgcn_mfma_f32_16x16x32_bf16(
                    a[fm], b[fn], acc[fm][fn], 0, 0, 0);
    }

    const float SQ2 = 1.4142135623730951f;
    #pragma unroll
    for (int fm = 0; fm < 2; ++fm)
        #pragma unroll
        for (int fn = 0; fn < 4; ++fn)
            #pragma unroll
            for (int j = 0; j < 4; ++j) {
                const int rl  = wm*32 + fm*16 + lg*4 + j;
                const int col = wn*64 + fn*16 + l15;
                ys[rl][col] = acc[fm][fn][j] + bback[col]
                            + SQ2 * x[((size_t)(row0 + rl)) * IFZ + col];
            }
    __syncthreads();

    {
        const int row = tid >> 2, q = tid & 3;
        float s1 = 0.f, s2 = 0.f;
        #pragma unroll
        for (int i = 0; i < 32; ++i) {
            const float yv = ys[row][q*32 + i];
            s1 += yv; s2 += yv*yv;
        }
        s1 += __shfl_xor(s1, 1); s2 += __shfl_xor(s2, 1);
        s1 += __shfl_xor(s1, 2); s2 += __shfl_xor(s2, 2);
        if (q == 0) {
            const float mean = s1 * (1.f/IFZ);
            const float var  = s2 * (1.f/IFZ) - mean*mean;
            st[row][0] = mean;
            st[row][1] = rsqrtf(var + 1e-5f);
        }
    }
    __syncthreads();

    {
        const int row = tid >> 2, q = tid & 3;
        const float mean = st[row][0], rstd = st[row][1];
        const float4* gmv = (const float4*)(gamma + q*32);
        const float4* btv = (const float4*)(beta  + q*32);
        float4* ov = (float4*)(out + ((size_t)(row0 + row)) * IFZ + q*32);
        #pragma unroll
        for (int i8 = 0; i8 < 8; ++i8) {
            const float4 g4 = gmv[i8], b4 = btv[i8];
            const float4 yv = *(const float4*)&ys[row][q*32 + i8*4];
            float4 r;
            r.x = g4.x*(yv.x-mean)*rstd + b4.x;
            r.y = g4.y*(yv.y-mean)*rstd + b4.y;
            r.z = g4.z*(yv.z-mean)*rstd + b4.z;
            r.w = g4.w*(yv.w-mean)*rstd + b4.w;
            ov[i8] = r;
        }
    }
}

// ---------------------------------------------------------------------------
extern "C" void kernel_launch(void* const* d_in, const int* in_sizes, int n_in,
                              void* d_out, int out_size, void* d_ws, size_t ws_size,
                              hipStream_t stream) {
    const float* x     = (const float*)d_in[0];
    const int*   edge  = (const int*)  d_in[1];
    const float* Wq    = (const float*)d_in[2];
    const float* Wk    = (const float*)d_in[3];
    const float* Wv    = (const float*)d_in[4];
    const float* Wb    = (const float*)d_in[5];
    const float* Wg    = (const float*)d_in[6];
    const float* bg    = (const float*)d_in[7];
    const float* Wback = (const float*)d_in[8];
    const float* bback = (const float*)d_in[9];
    const float* gamma = (const float*)d_in[10];
    const float* beta  = (const float*)d_in[11];
    float* out = (float*)d_out;

    const size_t RE = (size_t)ROWS * IFZ;   // 5,242,880 elements
    unsigned short* qb   = (unsigned short*)d_ws;
    unsigned short* kb   = qb + RE;
    unsigned short* vb   = kb + RE;
    unsigned short* gb   = vb + RE;
    unsigned short* obuf = gb + RE;
    unsigned short* xb   = obuf + RE;        // dead after proj_gemm
    unsigned*       ctxnb= (unsigned*)xb;    // aliases xb (ROWS*64 uints == RE shorts)
    unsigned short* Wt   = xb + RE;          // 512*128
    unsigned short* Wbt  = Wt + 512*128;     // 128*128
    float*          bbuf = (float*)(Wbt + 128*128);   // ROWS*4 f32
    float*          ssf  = bbuf + (size_t)ROWS*4;     // ROWS*80 f32 (13.1 MB)
    unsigned*       wsfu = (unsigned*)(ssf + (size_t)ROWS*80);  // ROWS*40 uints (6.6 MB)
    int*            cnt  = (int*)(wsfu + (size_t)ROWS*40);      // NN
    int*            inv  = cnt + NN;                            // NN*NSLOT
    // total ws use ~84.3 MB

    prep_x     <<<ROWS*IFZ/(256*8), 256, 0, stream>>>(x, xb);
    wtrans     <<<(512*128 + 128*128)/256, 256, 0, stream>>>(Wq, Wk, Wv, Wg, Wback, Wt, Wbt);
    bproj      <<<ROWS/256, 256, 0, stream>>>(xb, Wb, bbuf);
    proj_gemm  <<<dim3(ROWS/128, 4), 256, 0, stream>>>(xb, Wt, bg, qb, kb, vb, gb);
    zero_cnt   <<<NN/256, 256, 0, stream>>>(cnt);
    build_inv  <<<ROWS/256, 256, 0, stream>>>(edge, cnt, inv);
    sself_kernel<<<NN, 256, 0, stream>>>(qb, kb, bbuf, ssf);
    scatter_nb <<<NN, 256, 0, stream>>>(qb, kb, vb, bbuf, ssf, cnt, inv, wsfu, ctxnb);
    finalize_kernel<<<NN, 256, 0, stream>>>(vb, gb, wsfu, ctxnb, obuf);
    back_ln_kernel<<<ROWS/64, 256, 0, stream>>>(obuf, Wbt, x, bback, gamma, beta, out);
}

// Round 7
// 130.093 us; speedup vs baseline: 1.2416x; 1.2416x over previous
//
#include <hip/hip_runtime.h>
#include <math.h>

#define NN   2048
#define KZ   20
#define IFZ  128
#define AHZ  4
#define AFZ  32
#define ROWS (NN*KZ)           // 40960
#define TWO_KZ (2*KZ)          // 40

typedef __attribute__((ext_vector_type(8))) short short8v;   // 8 bf16 = 4 VGPR
typedef __attribute__((ext_vector_type(4))) float f32x4;     // MFMA acc

__device__ __forceinline__ float blo(unsigned int u) {      // low bf16 of packed pair
    union { unsigned int i; float f; } x; x.i = u << 16; return x.f;
}
__device__ __forceinline__ float bhi(unsigned int u) {      // high bf16 of packed pair
    union { unsigned int i; float f; } x; x.i = u & 0xffff0000u; return x.f;
}
__device__ __forceinline__ unsigned short f2b(float f) {
    union { float f; unsigned int i; } x; x.f = f;
    unsigned int r = x.i + 0x7fffu + ((x.i >> 16) & 1u);
    return (unsigned short)(r >> 16);
}
__device__ __forceinline__ unsigned pack2(float a, float b) {
    return (unsigned)f2b(a) | ((unsigned)f2b(b) << 16);
}

// ---------------------------------------------------------------------------
// prep_x: x (f32, ROWS x 128) -> xb (bf16). 8 elems/thread.
// ---------------------------------------------------------------------------
__global__ __launch_bounds__(256) void prep_x(const float* __restrict__ x,
                                              unsigned short* __restrict__ xb)
{
    const int gid = blockIdx.x * 256 + threadIdx.x;        // 0 .. ROWS*IFZ/8
    const float4* src = (const float4*)x;
    float4 v0 = src[gid * 2];
    float4 v1 = src[gid * 2 + 1];
    uint4 o;
    o.x = pack2(v0.x, v0.y);
    o.y = pack2(v0.z, v0.w);
    o.z = pack2(v1.x, v1.y);
    o.w = pack2(v1.z, v1.w);
    ((uint4*)xb)[gid] = o;
}

// ---------------------------------------------------------------------------
// wtrans: build transposed bf16 weights.
// ---------------------------------------------------------------------------
__global__ __launch_bounds__(256) void wtrans(
    const float* __restrict__ Wq, const float* __restrict__ Wk,
    const float* __restrict__ Wv, const float* __restrict__ Wg,
    const float* __restrict__ Wback,
    unsigned short* __restrict__ Wt, unsigned short* __restrict__ Wbt)
{
    const int gid = blockIdx.x * 256 + threadIdx.x;
    if (gid < 512 * 128) {
        const int n = gid >> 7, k = gid & 127;
        const float* W; int c;
        if      (n < 128) { W = Wq; c = n; }
        else if (n < 256) { W = Wk; c = n - 128; }
        else if (n < 384) { W = Wv; c = n - 256; }
        else              { W = Wg; c = n - 384; }
        Wt[gid] = f2b(W[k * 128 + c]);
    } else {
        const int g2 = gid - 512 * 128;
        const int n = g2 >> 7, k = g2 & 127;
        Wbt[g2] = f2b(Wback[k * 128 + n]);
    }
}

// ---------------------------------------------------------------------------
// bproj: b = xb @ Wb  (ROWS x 4), f32 accum from bf16 x. One row per thread.
// ---------------------------------------------------------------------------
__global__ __launch_bounds__(256) void bproj(const unsigned short* __restrict__ xb,
                                             const float* __restrict__ Wb,
                                             float* __restrict__ bbuf)
{
    const int row = blockIdx.x * 256 + threadIdx.x;        // 0 .. ROWS
    const unsigned* xv = (const unsigned*)xb + (size_t)row * 64;
    const float4* wv = (const float4*)Wb;                  // Wb[k][0..3]
    float4 acc = make_float4(0.f, 0.f, 0.f, 0.f);
    #pragma unroll
    for (int u = 0; u < 64; ++u) {
        const unsigned xu = xv[u];
        const float x0 = blo(xu), x1 = bhi(xu);
        const float4 w0 = wv[2*u], w1 = wv[2*u+1];
        acc.x += x0*w0.x + x1*w1.x;
        acc.y += x0*w0.y + x1*w1.y;
        acc.z += x0*w0.z + x1*w1.z;
        acc.w += x0*w0.w + x1*w1.w;
    }
    ((float4*)bbuf)[row] = acc;
}

// ---------------------------------------------------------------------------
// proj_gemm: [q|k|v|g] = xb @ Wt^T, MFMA 16x16x32 bf16, no LDS.
// SWAPPED operands: acc = mfma(b, a) computes C^T, so each lane holds 4
// CONSECUTIVE COLUMNS of one output row -> packed uint2 (4 bf16, 8B) stores,
// 16 per thread instead of 64 scalar 2B stores.
// ---------------------------------------------------------------------------
__global__ __launch_bounds__(256) void proj_gemm(
    const unsigned short* __restrict__ xb, const unsigned short* __restrict__ Wt,
    const float* __restrict__ bg,
    unsigned short* __restrict__ qb, unsigned short* __restrict__ kb,
    unsigned short* __restrict__ vb, unsigned short* __restrict__ gb)
{
    const int row0 = blockIdx.x * 128;
    const int col0 = blockIdx.y * 128;      // buffer select
    const int wid  = threadIdx.x >> 6;
    const int lane = threadIdx.x & 63;
    const int wm = wid >> 1, wn = wid & 1;
    const int l15 = lane & 15, lg = lane >> 4;

    f32x4 acc[4][4];
    #pragma unroll
    for (int i = 0; i < 4; ++i)
        #pragma unroll
        for (int j = 0; j < 4; ++j) acc[i][j] = (f32x4){0.f,0.f,0.f,0.f};

    const unsigned short* Ab = xb + ((size_t)(row0 + wm*64 + l15)) * IFZ + lg*8;
    const unsigned short* Bb = Wt + ((size_t)(col0 + wn*64 + l15)) * IFZ + lg*8;

    #pragma unroll
    for (int ks = 0; ks < 4; ++ks) {
        short8v a[4], b[4];
        #pragma unroll
        for (int f = 0; f < 4; ++f) {
            a[f] = *((const short8v*)(Ab + (size_t)f*16*IFZ + ks*32));
            b[f] = *((const short8v*)(Bb + (size_t)f*16*IFZ + ks*32));
        }
        #pragma unroll
        for (int fm = 0; fm < 4; ++fm)
            #pragma unroll
            for (int fn = 0; fn < 4; ++fn)
                acc[fm][fn] = __builtin_amdgcn_mfma_f32_16x16x32_bf16(
                    b[fn], a[fm], acc[fm][fn], 0, 0, 0);   // SWAPPED -> C^T frag
    }

    unsigned short* ob;
    switch (blockIdx.y) { case 0: ob = qb; break; case 1: ob = kb; break;
                          case 2: ob = vb; break; default: ob = gb; break; }
    const bool gate = (blockIdx.y == 3);

    #pragma unroll
    for (int fm = 0; fm < 4; ++fm) {
        const int row = row0 + wm*64 + fm*16 + l15;
        unsigned short* rp = ob + (size_t)row * IFZ;
        #pragma unroll
        for (int fn = 0; fn < 4; ++fn) {
            const int cbase = wn*64 + fn*16 + lg*4;
            float v0 = acc[fm][fn][0], v1 = acc[fm][fn][1];
            float v2 = acc[fm][fn][2], v3 = acc[fm][fn][3];
            if (gate) {
                const float4 bg4 = *(const float4*)(bg + cbase);
                v0 = 1.f/(1.f + __expf(-(v0 + bg4.x)));
                v1 = 1.f/(1.f + __expf(-(v1 + bg4.y)));
                v2 = 1.f/(1.f + __expf(-(v2 + bg4.z)));
                v3 = 1.f/(1.f + __expf(-(v3 + bg4.w)));
            }
            uint2 o;
            o.x = pack2(v0, v1);
            o.y = pack2(v2, v3);
            *(uint2*)(rp + cbase) = o;
        }
    }
}

// ---------------------------------------------------------------------------
// attn (R3 best: 57 us): one block per node. Packed-bf16 LDS staging with
// per-head pad-1 layout [kk][a][17] uints -> conflict-free, ~30 KB LDS.
// Branch-free self/neighbor score loops; phase 3 on column pairs.
// ---------------------------------------------------------------------------
__global__ __launch_bounds__(256) void attn_kernel(
    const unsigned short* __restrict__ qb, const unsigned short* __restrict__ kb,
    const unsigned short* __restrict__ vb, const unsigned short* __restrict__ gb,
    const float* __restrict__ bbuf, const int* __restrict__ edge,
    unsigned short* __restrict__ obuf)
{
    const int n   = blockIdx.x;
    const int tid = threadIdx.x;

    __shared__ unsigned qsu[KZ*68];      // [kk][a][17] packed bf16 pairs
    __shared__ unsigned ksu[KZ*68];
    __shared__ unsigned vsu[KZ*68];
    __shared__ float    sc[KZ][AHZ][41];
    __shared__ float    bs[KZ*AHZ];
    __shared__ int      es[KZ];

    const size_t base  = (size_t)n * (KZ*IFZ);
    const size_t base2 = base >> 1;              // uint index

    {
        const uint4* qsrc = (const uint4*)(qb + base);
        const uint4* ksrc = (const uint4*)(kb + base);
        const uint4* vsrc = (const uint4*)(vb + base);
        for (int i = tid; i < KZ*16; i += 256) {
            const int r = i >> 4, u4 = i & 15;
            const int d = r*68 + (u4 >> 2)*17 + (u4 & 3)*4;
            uint4 v;
            v = qsrc[i]; qsu[d]=v.x; qsu[d+1]=v.y; qsu[d+2]=v.z; qsu[d+3]=v.w;
            v = ksrc[i]; ksu[d]=v.x; ksu[d+1]=v.y; ksu[d+2]=v.z; ksu[d+3]=v.w;
            v = vsrc[i]; vsu[d]=v.x; vsu[d+1]=v.y; vsu[d+2]=v.z; vsu[d+3]=v.w;
        }
    }
    if (tid < KZ)      es[tid] = edge[n*KZ + tid];
    if (tid < KZ*AHZ)  bs[tid] = bbuf[(size_t)n*(KZ*AHZ) + tid];
    __syncthreads();

    const float rscale = 0.17677669529663687f;  // 1/sqrt(32)

    // Phase 1a: self scores. it = kk*80 + j*4 + a (1600 items)
    for (int it = tid; it < KZ*KZ*AHZ; it += 256) {
        const int a  = it & 3;
        const int j  = (it >> 2) % KZ;
        const int kk = it / (KZ*AHZ);
        const unsigned* qrow = &qsu[kk*68 + a*17];
        const unsigned* krow = &ksu[j*68 + a*17];
        float s = 0.f;
        #pragma unroll
        for (int c2 = 0; c2 < 16; ++c2) {
            const unsigned qu = qrow[c2], ku = krow[c2];
            s += blo(qu)*blo(ku) + bhi(qu)*bhi(ku);
        }
        sc[kk][a][j] = s*rscale + bs[j*AHZ + a];
    }

    // Phase 1b: neighbor scores. it = kk*80 + jj*4 + a (1600 items)
    for (int it = tid; it < KZ*KZ*AHZ; it += 256) {
        const int a  = it & 3;
        const int jj = (it >> 2) % KZ;
        const int kk = it / (KZ*AHZ);
        const int e  = es[kk];
        const unsigned* qrow = &qsu[kk*68 + a*17];
        const uint4* kp4 = (const uint4*)(kb + ((size_t)e*KZ + jj)*IFZ + a*AFZ);
        float s = 0.f;
        #pragma unroll
        for (int c8 = 0; c8 < 4; ++c8) {
            const uint4 kv = kp4[c8];
            const unsigned q0 = qrow[c8*4], q1 = qrow[c8*4+1];
            const unsigned q2 = qrow[c8*4+2], q3 = qrow[c8*4+3];
            s += blo(q0)*blo(kv.x) + bhi(q0)*bhi(kv.x)
               + blo(q1)*blo(kv.y) + bhi(q1)*bhi(kv.y)
               + blo(q2)*blo(kv.z) + bhi(q2)*bhi(kv.z)
               + blo(q3)*blo(kv.w) + bhi(q3)*bhi(kv.w);
        }
        sc[kk][a][KZ + jj] = s*rscale + bbuf[((size_t)e*KZ + jj)*AHZ + a];
    }
    __syncthreads();

    // Phase 2: softmax over the 40 keys, one thread per (kk,a) row.
    if (tid < KZ*AHZ) {
        const int kk = tid >> 2, a = tid & 3;
        float* row = &sc[kk][a][0];
        float m = row[0];
        #pragma unroll
        for (int j = 1; j < TWO_KZ; ++j) m = fmaxf(m, row[j]);
        float ssum = 0.f;
        #pragma unroll
        for (int j = 0; j < TWO_KZ; ++j) { const float e = __expf(row[j]-m); row[j] = e; ssum += e; }
        const float inv = 1.f/ssum;
        #pragma unroll
        for (int j = 0; j < TWO_KZ; ++j) row[j] *= inv;
    }
    __syncthreads();

    // Phase 3: context + gate, column pairs. it = kk*64 + c2 (1280 items)
    for (int it = tid; it < KZ*64; it += 256) {
        const int kk = it >> 6;
        const int c2 = it & 63;          // column pair: cols {2c2, 2c2+1}
        const int a  = c2 >> 4;
        const float* wrow = &sc[kk][a][0];
        float acc0 = 0.f, acc1 = 0.f;
        const unsigned* vrow = &vsu[a*17 + (c2 & 15)];
        #pragma unroll
        for (int j = 0; j < KZ; ++j) {
            const unsigned u = vrow[j*68];
            const float w = wrow[j];
            acc0 += w*blo(u); acc1 += w*bhi(u);
        }
        const int e = es[kk];
        const unsigned* vpu = (const unsigned*)vb + (size_t)e*(KZ*64) + c2;
        #pragma unroll
        for (int j = 0; j < KZ; ++j) {
            const unsigned u = vpu[j*64];
            const float w = wrow[KZ + j];
            acc0 += w*blo(u); acc1 += w*bhi(u);
        }
        const unsigned gu = ((const unsigned*)gb)[base2 + it];
        const float o0 = acc0 * blo(gu);
        const float o1 = acc1 * bhi(gu);
        ((unsigned*)obuf)[base2 + it] = pack2(o0, o1);
    }
}

// ---------------------------------------------------------------------------
// back_ln: y = ob @ Wbt^T + bback + sqrt2*x, then LayerNorm. MFMA, BM=64.
// ---------------------------------------------------------------------------
__global__ __launch_bounds__(256) void back_ln_kernel(
    const unsigned short* __restrict__ ob, const unsigned short* __restrict__ Wbt,
    const float* __restrict__ x, const float* __restrict__ bback,
    const float* __restrict__ gamma, const float* __restrict__ beta,
    float* __restrict__ out)
{
    __shared__ float ys[64][132];
    __shared__ float st[64][2];
    const int row0 = blockIdx.x * 64;
    const int tid  = threadIdx.x;
    const int wid  = tid >> 6;
    const int lane = tid & 63;
    const int wm = wid >> 1, wn = wid & 1;
    const int l15 = lane & 15, lg = lane >> 4;

    f32x4 acc[2][4];
    #pragma unroll
    for (int i = 0; i < 2; ++i)
        #pragma unroll
        for (int j = 0; j < 4; ++j) acc[i][j] = (f32x4){0.f,0.f,0.f,0.f};

    const unsigned short* Ab = ob  + ((size_t)(row0 + wm*32 + l15)) * IFZ + lg*8;
    const unsigned short* Bb = Wbt + ((size_t)(wn*64 + l15)) * IFZ + lg*8;

    #pragma unroll
    for (int ksI = 0; ksI < 4; ++ksI) {
        short8v a[2], b[4];
        #pragma unroll
        for (int f = 0; f < 2; ++f) a[f] = *((const short8v*)(Ab + (size_t)f*16*IFZ + ksI*32));
        #pragma unroll
        for (int f = 0; f < 4; ++f) b[f] = *((const short8v*)(Bb + (size_t)f*16*IFZ + ksI*32));
        #pragma unroll
        for (int fm = 0; fm < 2; ++fm)
            #pragma unroll
            for (int fn = 0; fn < 4; ++fn)
                acc[fm][fn] = __builtin_amdgcn_mfma_f32_16x16x32_bf16(
                    a[fm], b[fn], acc[fm][fn], 0, 0, 0);
    }

    const float SQ2 = 1.4142135623730951f;
    #pragma unroll
    for (int fm = 0; fm < 2; ++fm)
        #pragma unroll
        for (int fn = 0; fn < 4; ++fn)
            #pragma unroll
            for (int j = 0; j < 4; ++j) {
                const int rl  = wm*32 + fm*16 + lg*4 + j;
                const int col = wn*64 + fn*16 + l15;
                ys[rl][col] = acc[fm][fn][j] + bback[col]
                            + SQ2 * x[((size_t)(row0 + rl)) * IFZ + col];
            }
    __syncthreads();

    {
        const int row = tid >> 2, q = tid & 3;
        float s1 = 0.f, s2 = 0.f;
        #pragma unroll
        for (int i = 0; i < 32; ++i) {
            const float yv = ys[row][q*32 + i];
            s1 += yv; s2 += yv*yv;
        }
        s1 += __shfl_xor(s1, 1); s2 += __shfl_xor(s2, 1);
        s1 += __shfl_xor(s1, 2); s2 += __shfl_xor(s2, 2);
        if (q == 0) {
            const float mean = s1 * (1.f/IFZ);
            const float var  = s2 * (1.f/IFZ) - mean*mean;
            st[row][0] = mean;
            st[row][1] = rsqrtf(var + 1e-5f);
        }
    }
    __syncthreads();

    {
        const int row = tid >> 2, q = tid & 3;
        const float mean = st[row][0], rstd = st[row][1];
        const float4* gmv = (const float4*)(gamma + q*32);
        const float4* btv = (const float4*)(beta  + q*32);
        float4* ov = (float4*)(out + ((size_t)(row0 + row)) * IFZ + q*32);
        #pragma unroll
        for (int i8 = 0; i8 < 8; ++i8) {
            const float4 g4 = gmv[i8], b4 = btv[i8];
            const float4 yv = *(const float4*)&ys[row][q*32 + i8*4];
            float4 r;
            r.x = g4.x*(yv.x-mean)*rstd + b4.x;
            r.y = g4.y*(yv.y-mean)*rstd + b4.y;
            r.z = g4.z*(yv.z-mean)*rstd + b4.z;
            r.w = g4.w*(yv.w-mean)*rstd + b4.w;
            ov[i8] = r;
        }
    }
}

// ---------------------------------------------------------------------------
extern "C" void kernel_launch(void* const* d_in, const int* in_sizes, int n_in,
                              void* d_out, int out_size, void* d_ws, size_t ws_size,
                              hipStream_t stream) {
    const float* x     = (const float*)d_in[0];
    const int*   edge  = (const int*)  d_in[1];
    const float* Wq    = (const float*)d_in[2];
    const float* Wk    = (const float*)d_in[3];
    const float* Wv    = (const float*)d_in[4];
    const float* Wb    = (const float*)d_in[5];
    const float* Wg    = (const float*)d_in[6];
    const float* bg    = (const float*)d_in[7];
    const float* Wback = (const float*)d_in[8];
    const float* bback = (const float*)d_in[9];
    const float* gamma = (const float*)d_in[10];
    const float* beta  = (const float*)d_in[11];
    float* out = (float*)d_out;

    const size_t RE = (size_t)ROWS * IFZ;   // 5,242,880 elements
    unsigned short* qb  = (unsigned short*)d_ws;
    unsigned short* kb  = qb + RE;
    unsigned short* vb  = kb + RE;
    unsigned short* gb  = vb + RE;
    unsigned short* obuf= gb + RE;
    unsigned short* xb  = obuf + RE;
    unsigned short* Wt  = xb + RE;          // 512*128
    unsigned short* Wbt = Wt + 512*128;     // 128*128
    float*          bbuf= (float*)(Wbt + 128*128);   // ROWS*4 f32
    // total ws use ~63.7 MB

    prep_x     <<<ROWS*IFZ/(256*8), 256, 0, stream>>>(x, xb);
    wtrans     <<<(512*128 + 128*128)/256, 256, 0, stream>>>(Wq, Wk, Wv, Wg, Wback, Wt, Wbt);
    bproj      <<<ROWS/256, 256, 0, stream>>>(xb, Wb, bbuf);
    proj_gemm  <<<dim3(ROWS/128, 4), 256, 0, stream>>>(xb, Wt, bg, qb, kb, vb, gb);
    attn_kernel<<<NN, 256, 0, stream>>>(qb, kb, vb, gb, bbuf, edge, obuf);
    back_ln_kernel<<<ROWS/64, 256, 0, stream>>>(obuf, Wbt, x, bback, gamma, beta, out);
}

// Round 8
// 128.850 us; speedup vs baseline: 1.2536x; 1.0096x over previous
//
#include <hip/hip_runtime.h>
#include <math.h>

#define NN   2048
#define KZ   20
#define IFZ  128
#define AHZ  4
#define AFZ  32
#define ROWS (NN*KZ)           // 40960
#define TWO_KZ (2*KZ)          // 40

typedef __attribute__((ext_vector_type(8))) short short8v;   // 8 bf16 = 4 VGPR
typedef __attribute__((ext_vector_type(4))) float f32x4;     // MFMA acc
typedef __attribute__((ext_vector_type(2))) float f32x2;

__device__ __forceinline__ float blo(unsigned int u) {      // low bf16 of packed pair
    union { unsigned int i; float f; } x; x.i = u << 16; return x.f;
}
__device__ __forceinline__ float bhi(unsigned int u) {      // high bf16 of packed pair
    union { unsigned int i; float f; } x; x.i = u & 0xffff0000u; return x.f;
}
__device__ __forceinline__ unsigned short f2b(float f) {
    union { float f; unsigned int i; } x; x.f = f;
    unsigned int r = x.i + 0x7fffu + ((x.i >> 16) & 1u);
    return (unsigned short)(r >> 16);
}
__device__ __forceinline__ unsigned pack2(float a, float b) {
    return (unsigned)f2b(a) | ((unsigned)f2b(b) << 16);
}

// ---------------------------------------------------------------------------
// setup: fused prep_x (blocks 0..2559) | wtrans (2560..2879) | bproj f32
// (2880..3039). All three independent (bproj reads f32 x, not xb).
// ---------------------------------------------------------------------------
__global__ __launch_bounds__(256) void setup_kernel(
    const float* __restrict__ x,
    const float* __restrict__ Wq, const float* __restrict__ Wk,
    const float* __restrict__ Wv, const float* __restrict__ Wg,
    const float* __restrict__ Wback, const float* __restrict__ Wb,
    unsigned short* __restrict__ xb, unsigned short* __restrict__ Wt,
    unsigned short* __restrict__ Wbt, float* __restrict__ bbuf)
{
    const int b   = blockIdx.x;
    const int tid = threadIdx.x;

    if (b < 2560) {                       // ---- prep_x: 8 elems/thread
        const int gid = b * 256 + tid;
        const float4* src = (const float4*)x;
        float4 v0 = src[gid * 2];
        float4 v1 = src[gid * 2 + 1];
        uint4 o;
        o.x = pack2(v0.x, v0.y);
        o.y = pack2(v0.z, v0.w);
        o.z = pack2(v1.x, v1.y);
        o.w = pack2(v1.z, v1.w);
        ((uint4*)xb)[gid] = o;
    } else if (b < 2880) {                // ---- wtrans
        const int gid = (b - 2560) * 256 + tid;
        if (gid < 512 * 128) {
            const int n = gid >> 7, k = gid & 127;
            const float* W; int c;
            if      (n < 128) { W = Wq; c = n; }
            else if (n < 256) { W = Wk; c = n - 128; }
            else if (n < 384) { W = Wv; c = n - 256; }
            else              { W = Wg; c = n - 384; }
            Wt[gid] = f2b(W[k * 128 + c]);
        } else {
            const int g2 = gid - 512 * 128;
            const int n = g2 >> 7, k = g2 & 127;
            Wbt[g2] = f2b(Wback[k * 128 + n]);
        }
    } else {                              // ---- bproj (f32 x)
        const int row = (b - 2880) * 256 + tid;
        const float4* xv = (const float4*)(x + (size_t)row * IFZ);
        const float4* wv = (const float4*)Wb;
        float4 acc = make_float4(0.f, 0.f, 0.f, 0.f);
        #pragma unroll
        for (int k4 = 0; k4 < 32; ++k4) {
            const float4 xc = xv[k4];
            float4 w;
            w = wv[k4*4+0]; acc.x += xc.x*w.x; acc.y += xc.x*w.y; acc.z += xc.x*w.z; acc.w += xc.x*w.w;
            w = wv[k4*4+1]; acc.x += xc.y*w.x; acc.y += xc.y*w.y; acc.z += xc.y*w.z; acc.w += xc.y*w.w;
            w = wv[k4*4+2]; acc.x += xc.z*w.x; acc.y += xc.z*w.y; acc.z += xc.z*w.z; acc.w += xc.z*w.w;
            w = wv[k4*4+3]; acc.x += xc.w*w.x; acc.y += xc.w*w.y; acc.z += xc.w*w.z; acc.w += xc.w*w.w;
        }
        ((float4*)bbuf)[row] = acc;
    }
}

// ---------------------------------------------------------------------------
// proj_gemm: [q|k|v|g] = xb @ Wt^T, MFMA 16x16x32 bf16, swapped operands
// (C^T fragment -> 4 consecutive cols/lane -> packed uint2 stores).
// blockIdx.y==1 additionally emits kf8 (OCP e4m3 shadow of K).
// ---------------------------------------------------------------------------
__global__ __launch_bounds__(256) void proj_gemm(
    const unsigned short* __restrict__ xb, const unsigned short* __restrict__ Wt,
    const float* __restrict__ bg,
    unsigned short* __restrict__ qb, unsigned short* __restrict__ kb,
    unsigned short* __restrict__ vb, unsigned short* __restrict__ gb,
    unsigned char* __restrict__ kf8)
{
    const int row0 = blockIdx.x * 128;
    const int col0 = blockIdx.y * 128;      // buffer select
    const int wid  = threadIdx.x >> 6;
    const int lane = threadIdx.x & 63;
    const int wm = wid >> 1, wn = wid & 1;
    const int l15 = lane & 15, lg = lane >> 4;

    f32x4 acc[4][4];
    #pragma unroll
    for (int i = 0; i < 4; ++i)
        #pragma unroll
        for (int j = 0; j < 4; ++j) acc[i][j] = (f32x4){0.f,0.f,0.f,0.f};

    const unsigned short* Ab = xb + ((size_t)(row0 + wm*64 + l15)) * IFZ + lg*8;
    const unsigned short* Bb = Wt + ((size_t)(col0 + wn*64 + l15)) * IFZ + lg*8;

    #pragma unroll
    for (int ks = 0; ks < 4; ++ks) {
        short8v a[4], b[4];
        #pragma unroll
        for (int f = 0; f < 4; ++f) {
            a[f] = *((const short8v*)(Ab + (size_t)f*16*IFZ + ks*32));
            b[f] = *((const short8v*)(Bb + (size_t)f*16*IFZ + ks*32));
        }
        #pragma unroll
        for (int fm = 0; fm < 4; ++fm)
            #pragma unroll
            for (int fn = 0; fn < 4; ++fn)
                acc[fm][fn] = __builtin_amdgcn_mfma_f32_16x16x32_bf16(
                    b[fn], a[fm], acc[fm][fn], 0, 0, 0);   // SWAPPED -> C^T frag
    }

    unsigned short* ob;
    switch (blockIdx.y) { case 0: ob = qb; break; case 1: ob = kb; break;
                          case 2: ob = vb; break; default: ob = gb; break; }
    const bool gate = (blockIdx.y == 3);
    const bool isk  = (blockIdx.y == 1);

    #pragma unroll
    for (int fm = 0; fm < 4; ++fm) {
        const int row = row0 + wm*64 + fm*16 + l15;
        unsigned short* rp = ob + (size_t)row * IFZ;
        #pragma unroll
        for (int fn = 0; fn < 4; ++fn) {
            const int cbase = wn*64 + fn*16 + lg*4;
            float v0 = acc[fm][fn][0], v1 = acc[fm][fn][1];
            float v2 = acc[fm][fn][2], v3 = acc[fm][fn][3];
            if (gate) {
                const float4 bg4 = *(const float4*)(bg + cbase);
                v0 = 1.f/(1.f + __expf(-(v0 + bg4.x)));
                v1 = 1.f/(1.f + __expf(-(v1 + bg4.y)));
                v2 = 1.f/(1.f + __expf(-(v2 + bg4.z)));
                v3 = 1.f/(1.f + __expf(-(v3 + bg4.w)));
            }
            uint2 o;
            o.x = pack2(v0, v1);
            o.y = pack2(v2, v3);
            *(uint2*)(rp + cbase) = o;
            if (isk) {
                int p = __builtin_amdgcn_cvt_pk_fp8_f32(v0, v1, 0, false);
                p     = __builtin_amdgcn_cvt_pk_fp8_f32(v2, v3, p, true);
                *(unsigned*)(kf8 + (size_t)row*128 + cbase) = (unsigned)p;
            }
        }
    }
}

// ---------------------------------------------------------------------------
// attn: R3-best structure; neighbor K scores now read the fp8 shadow (kf8),
// halving the K-gather bytes. Self K/Q/V stay bf16 in LDS.
// ---------------------------------------------------------------------------
__global__ __launch_bounds__(256) void attn_kernel(
    const unsigned short* __restrict__ qb, const unsigned short* __restrict__ kb,
    const unsigned short* __restrict__ vb, const unsigned short* __restrict__ gb,
    const float* __restrict__ bbuf, const int* __restrict__ edge,
    const unsigned char* __restrict__ kf8,
    unsigned short* __restrict__ obuf)
{
    const int n   = blockIdx.x;
    const int tid = threadIdx.x;

    __shared__ unsigned qsu[KZ*68];      // [kk][a][17] packed bf16 pairs
    __shared__ unsigned ksu[KZ*68];
    __shared__ unsigned vsu[KZ*68];
    __shared__ float    sc[KZ][AHZ][41];
    __shared__ float    bs[KZ*AHZ];
    __shared__ int      es[KZ];

    const size_t base  = (size_t)n * (KZ*IFZ);
    const size_t base2 = base >> 1;              // uint index

    {
        const uint4* qsrc = (const uint4*)(qb + base);
        const uint4* ksrc = (const uint4*)(kb + base);
        const uint4* vsrc = (const uint4*)(vb + base);
        for (int i = tid; i < KZ*16; i += 256) {
            const int r = i >> 4, u4 = i & 15;
            const int d = r*68 + (u4 >> 2)*17 + (u4 & 3)*4;
            uint4 v;
            v = qsrc[i]; qsu[d]=v.x; qsu[d+1]=v.y; qsu[d+2]=v.z; qsu[d+3]=v.w;
            v = ksrc[i]; ksu[d]=v.x; ksu[d+1]=v.y; ksu[d+2]=v.z; ksu[d+3]=v.w;
            v = vsrc[i]; vsu[d]=v.x; vsu[d+1]=v.y; vsu[d+2]=v.z; vsu[d+3]=v.w;
        }
    }
    if (tid < KZ)      es[tid] = edge[n*KZ + tid];
    if (tid < KZ*AHZ)  bs[tid] = bbuf[(size_t)n*(KZ*AHZ) + tid];
    __syncthreads();

    const float rscale = 0.17677669529663687f;  // 1/sqrt(32)

    // Phase 1a: self scores. it = kk*80 + j*4 + a (1600 items)
    for (int it = tid; it < KZ*KZ*AHZ; it += 256) {
        const int a  = it & 3;
        const int j  = (it >> 2) % KZ;
        const int kk = it / (KZ*AHZ);
        const unsigned* qrow = &qsu[kk*68 + a*17];
        const unsigned* krow = &ksu[j*68 + a*17];
        float s = 0.f;
        #pragma unroll
        for (int c2 = 0; c2 < 16; ++c2) {
            const unsigned qu = qrow[c2], ku = krow[c2];
            s += blo(qu)*blo(ku) + bhi(qu)*bhi(ku);
        }
        sc[kk][a][j] = s*rscale + bs[j*AHZ + a];
    }

    // Phase 1b: neighbor scores from kf8. it = kk*80 + jj*4 + a (1600 items)
    for (int it = tid; it < KZ*KZ*AHZ; it += 256) {
        const int a  = it & 3;
        const int jj = (it >> 2) % KZ;
        const int kk = it / (KZ*AHZ);
        const int e  = es[kk];
        const unsigned* qrow = &qsu[kk*68 + a*17];
        const unsigned char* kp = kf8 + ((size_t)e*KZ + jj)*128 + a*32;
        const uint4 k1 = *(const uint4*)kp;
        const uint4 k2 = *(const uint4*)(kp + 16);
        float s = 0.f;
        unsigned ks_[8] = {k1.x, k1.y, k1.z, k1.w, k2.x, k2.y, k2.z, k2.w};
        #pragma unroll
        for (int u = 0; u < 8; ++u) {
            const f32x2 lo = __builtin_amdgcn_cvt_pk_f32_fp8(ks_[u], false);
            const f32x2 hi = __builtin_amdgcn_cvt_pk_f32_fp8(ks_[u], true);
            const unsigned q0 = qrow[2*u], q1 = qrow[2*u+1];
            s += blo(q0)*lo.x + bhi(q0)*lo.y + blo(q1)*hi.x + bhi(q1)*hi.y;
        }
        sc[kk][a][KZ + jj] = s*rscale + bbuf[((size_t)e*KZ + jj)*AHZ + a];
    }
    __syncthreads();

    // Phase 2: softmax over the 40 keys, one thread per (kk,a) row.
    if (tid < KZ*AHZ) {
        const int kk = tid >> 2, a = tid & 3;
        float* row = &sc[kk][a][0];
        float m = row[0];
        #pragma unroll
        for (int j = 1; j < TWO_KZ; ++j) m = fmaxf(m, row[j]);
        float ssum = 0.f;
        #pragma unroll
        for (int j = 0; j < TWO_KZ; ++j) { const float e = __expf(row[j]-m); row[j] = e; ssum += e; }
        const float inv = 1.f/ssum;
        #pragma unroll
        for (int j = 0; j < TWO_KZ; ++j) row[j] *= inv;
    }
    __syncthreads();

    // Phase 3: context + gate, column pairs. it = kk*64 + c2 (1280 items)
    for (int it = tid; it < KZ*64; it += 256) {
        const int kk = it >> 6;
        const int c2 = it & 63;          // column pair: cols {2c2, 2c2+1}
        const int a  = c2 >> 4;
        const float* wrow = &sc[kk][a][0];
        float acc0 = 0.f, acc1 = 0.f;
        const unsigned* vrow = &vsu[a*17 + (c2 & 15)];
        #pragma unroll
        for (int j = 0; j < KZ; ++j) {
            const unsigned u = vrow[j*68];
            const float w = wrow[j];
            acc0 += w*blo(u); acc1 += w*bhi(u);
        }
        const int e = es[kk];
        const unsigned* vpu = (const unsigned*)vb + (size_t)e*(KZ*64) + c2;
        #pragma unroll
        for (int j = 0; j < KZ; ++j) {
            const unsigned u = vpu[j*64];
            const float w = wrow[KZ + j];
            acc0 += w*blo(u); acc1 += w*bhi(u);
        }
        const unsigned gu = ((const unsigned*)gb)[base2 + it];
        const float o0 = acc0 * blo(gu);
        const float o1 = acc1 * bhi(gu);
        ((unsigned*)obuf)[base2 + it] = pack2(o0, o1);
    }
}

// ---------------------------------------------------------------------------
// back_ln: y = ob @ Wbt^T + bback + sqrt2*x, then LayerNorm. MFMA, BM=64.
// ---------------------------------------------------------------------------
__global__ __launch_bounds__(256) void back_ln_kernel(
    const unsigned short* __restrict__ ob, const unsigned short* __restrict__ Wbt,
    const float* __restrict__ x, const float* __restrict__ bback,
    const float* __restrict__ gamma, const float* __restrict__ beta,
    float* __restrict__ out)
{
    __shared__ float ys[64][132];
    __shared__ float st[64][2];
    const int row0 = blockIdx.x * 64;
    const int tid  = threadIdx.x;
    const int wid  = tid >> 6;
    const int lane = tid & 63;
    const int wm = wid >> 1, wn = wid & 1;
    const int l15 = lane & 15, lg = lane >> 4;

    f32x4 acc[2][4];
    #pragma unroll
    for (int i = 0; i < 2; ++i)
        #pragma unroll
        for (int j = 0; j < 4; ++j) acc[i][j] = (f32x4){0.f,0.f,0.f,0.f};

    const unsigned short* Ab = ob  + ((size_t)(row0 + wm*32 + l15)) * IFZ + lg*8;
    const unsigned short* Bb = Wbt + ((size_t)(wn*64 + l15)) * IFZ + lg*8;

    #pragma unroll
    for (int ksI = 0; ksI < 4; ++ksI) {
        short8v a[2], b[4];
        #pragma unroll
        for (int f = 0; f < 2; ++f) a[f] = *((const short8v*)(Ab + (size_t)f*16*IFZ + ksI*32));
        #pragma unroll
        for (int f = 0; f < 4; ++f) b[f] = *((const short8v*)(Bb + (size_t)f*16*IFZ + ksI*32));
        #pragma unroll
        for (int fm = 0; fm < 2; ++fm)
            #pragma unroll
            for (int fn = 0; fn < 4; ++fn)
                acc[fm][fn] = __builtin_amdgcn_mfma_f32_16x16x32_bf16(
                    a[fm], b[fn], acc[fm][fn], 0, 0, 0);
    }

    const float SQ2 = 1.4142135623730951f;
    #pragma unroll
    for (int fm = 0; fm < 2; ++fm)
        #pragma unroll
        for (int fn = 0; fn < 4; ++fn)
            #pragma unroll
            for (int j = 0; j < 4; ++j) {
                const int rl  = wm*32 + fm*16 + lg*4 + j;
                const int col = wn*64 + fn*16 + l15;
                ys[rl][col] = acc[fm][fn][j] + bback[col]
                            + SQ2 * x[((size_t)(row0 + rl)) * IFZ + col];
            }
    __syncthreads();

    {
        const int row = tid >> 2, q = tid & 3;
        float s1 = 0.f, s2 = 0.f;
        #pragma unroll
        for (int i = 0; i < 32; ++i) {
            const float yv = ys[row][q*32 + i];
            s1 += yv; s2 += yv*yv;
        }
        s1 += __shfl_xor(s1, 1); s2 += __shfl_xor(s2, 1);
        s1 += __shfl_xor(s1, 2); s2 += __shfl_xor(s2, 2);
        if (q == 0) {
            const float mean = s1 * (1.f/IFZ);
            const float var  = s2 * (1.f/IFZ) - mean*mean;
            st[row][0] = mean;
            st[row][1] = rsqrtf(var + 1e-5f);
        }
    }
    __syncthreads();

    {
        const int row = tid >> 2, q = tid & 3;
        const float mean = st[row][0], rstd = st[row][1];
        const float4* gmv = (const float4*)(gamma + q*32);
        const float4* btv = (const float4*)(beta  + q*32);
        float4* ov = (float4*)(out + ((size_t)(row0 + row)) * IFZ + q*32);
        #pragma unroll
        for (int i8 = 0; i8 < 8; ++i8) {
            const float4 g4 = gmv[i8], b4 = btv[i8];
            const float4 yv = *(const float4*)&ys[row][q*32 + i8*4];
            float4 r;
            r.x = g4.x*(yv.x-mean)*rstd + b4.x;
            r.y = g4.y*(yv.y-mean)*rstd + b4.y;
            r.z = g4.z*(yv.z-mean)*rstd + b4.z;
            r.w = g4.w*(yv.w-mean)*rstd + b4.w;
            ov[i8] = r;
        }
    }
}

// ---------------------------------------------------------------------------
extern "C" void kernel_launch(void* const* d_in, const int* in_sizes, int n_in,
                              void* d_out, int out_size, void* d_ws, size_t ws_size,
                              hipStream_t stream) {
    const float* x     = (const float*)d_in[0];
    const int*   edge  = (const int*)  d_in[1];
    const float* Wq    = (const float*)d_in[2];
    const float* Wk    = (const float*)d_in[3];
    const float* Wv    = (const float*)d_in[4];
    const float* Wb    = (const float*)d_in[5];
    const float* Wg    = (const float*)d_in[6];
    const float* bg    = (const float*)d_in[7];
    const float* Wback = (const float*)d_in[8];
    const float* bback = (const float*)d_in[9];
    const float* gamma = (const float*)d_in[10];
    const float* beta  = (const float*)d_in[11];
    float* out = (float*)d_out;

    const size_t RE = (size_t)ROWS * IFZ;   // 5,242,880 elements
    unsigned short* qb  = (unsigned short*)d_ws;
    unsigned short* kb  = qb + RE;
    unsigned short* vb  = kb + RE;
    unsigned short* gb  = vb + RE;
    unsigned short* obuf= gb + RE;
    unsigned short* xb  = obuf + RE;
    unsigned short* Wt  = xb + RE;          // 512*128
    unsigned short* Wbt = Wt + 512*128;     // 128*128
    float*          bbuf= (float*)(Wbt + 128*128);   // ROWS*4 f32
    unsigned char*  kf8 = (unsigned char*)(bbuf + (size_t)ROWS*4);  // ROWS*128 B
    // total ws use ~69 MB

    setup_kernel<<<3040, 256, 0, stream>>>(x, Wq, Wk, Wv, Wg, Wback, Wb,
                                           xb, Wt, Wbt, bbuf);
    proj_gemm  <<<dim3(ROWS/128, 4), 256, 0, stream>>>(xb, Wt, bg, qb, kb, vb, gb, kf8);
    attn_kernel<<<NN, 256, 0, stream>>>(qb, kb, vb, gb, bbuf, edge, kf8, obuf);
    back_ln_kernel<<<ROWS/64, 256, 0, stream>>>(obuf, Wbt, x, bback, gamma, beta, out);
}

// Round 9
// 123.926 us; speedup vs baseline: 1.3034x; 1.0397x over previous
//
#include <hip/hip_runtime.h>
#include <math.h>

#define NN   2048
#define KZ   20
#define IFZ  128
#define AHZ  4
#define AFZ  32
#define ROWS (NN*KZ)           // 40960
#define TWO_KZ (2*KZ)          // 40

typedef __attribute__((ext_vector_type(8))) short short8v;   // 8 bf16 = 4 VGPR
typedef __attribute__((ext_vector_type(4))) float f32x4;     // MFMA acc
typedef __attribute__((ext_vector_type(2))) float f32x2;

__device__ __forceinline__ float blo(unsigned int u) {      // low bf16 of packed pair
    union { unsigned int i; float f; } x; x.i = u << 16; return x.f;
}
__device__ __forceinline__ float bhi(unsigned int u) {      // high bf16 of packed pair
    union { unsigned int i; float f; } x; x.i = u & 0xffff0000u; return x.f;
}
__device__ __forceinline__ unsigned short f2b(float f) {
    union { float f; unsigned int i; } x; x.f = f;
    unsigned int r = x.i + 0x7fffu + ((x.i >> 16) & 1u);
    return (unsigned short)(r >> 16);
}
__device__ __forceinline__ unsigned pack2(float a, float b) {
    return (unsigned)f2b(a) | ((unsigned)f2b(b) << 16);
}

// ---------------------------------------------------------------------------
// setup: fused prep_x (blocks 0..2559) | wtrans (2560..2879) | bproj f32
// (2880..3039). All three independent (bproj reads f32 x, not xb).
// ---------------------------------------------------------------------------
__global__ __launch_bounds__(256) void setup_kernel(
    const float* __restrict__ x,
    const float* __restrict__ Wq, const float* __restrict__ Wk,
    const float* __restrict__ Wv, const float* __restrict__ Wg,
    const float* __restrict__ Wback, const float* __restrict__ Wb,
    unsigned short* __restrict__ xb, unsigned short* __restrict__ Wt,
    unsigned short* __restrict__ Wbt, float* __restrict__ bbuf)
{
    const int b   = blockIdx.x;
    const int tid = threadIdx.x;

    if (b < 2560) {                       // ---- prep_x: 8 elems/thread
        const int gid = b * 256 + tid;
        const float4* src = (const float4*)x;
        float4 v0 = src[gid * 2];
        float4 v1 = src[gid * 2 + 1];
        uint4 o;
        o.x = pack2(v0.x, v0.y);
        o.y = pack2(v0.z, v0.w);
        o.z = pack2(v1.x, v1.y);
        o.w = pack2(v1.z, v1.w);
        ((uint4*)xb)[gid] = o;
    } else if (b < 2880) {                // ---- wtrans
        const int gid = (b - 2560) * 256 + tid;
        if (gid < 512 * 128) {
            const int n = gid >> 7, k = gid & 127;
            const float* W; int c;
            if      (n < 128) { W = Wq; c = n; }
            else if (n < 256) { W = Wk; c = n - 128; }
            else if (n < 384) { W = Wv; c = n - 256; }
            else              { W = Wg; c = n - 384; }
            Wt[gid] = f2b(W[k * 128 + c]);
        } else {
            const int g2 = gid - 512 * 128;
            const int n = g2 >> 7, k = g2 & 127;
            Wbt[g2] = f2b(Wback[k * 128 + n]);
        }
    } else {                              // ---- bproj (f32 x)
        const int row = (b - 2880) * 256 + tid;
        const float4* xv = (const float4*)(x + (size_t)row * IFZ);
        const float4* wv = (const float4*)Wb;
        float4 acc = make_float4(0.f, 0.f, 0.f, 0.f);
        #pragma unroll
        for (int k4 = 0; k4 < 32; ++k4) {
            const float4 xc = xv[k4];
            float4 w;
            w = wv[k4*4+0]; acc.x += xc.x*w.x; acc.y += xc.x*w.y; acc.z += xc.x*w.z; acc.w += xc.x*w.w;
            w = wv[k4*4+1]; acc.x += xc.y*w.x; acc.y += xc.y*w.y; acc.z += xc.y*w.z; acc.w += xc.y*w.w;
            w = wv[k4*4+2]; acc.x += xc.z*w.x; acc.y += xc.z*w.y; acc.z += xc.z*w.z; acc.w += xc.z*w.w;
            w = wv[k4*4+3]; acc.x += xc.w*w.x; acc.y += xc.w*w.y; acc.z += xc.w*w.z; acc.w += xc.w*w.w;
        }
        ((float4*)bbuf)[row] = acc;
    }
}

// ---------------------------------------------------------------------------
// proj_gemm: [q|k|v|g] = xb @ Wt^T, MFMA 16x16x32 bf16, swapped operands
// (C^T fragment -> 4 consecutive cols/lane -> packed uint2 stores).
// blockIdx.y==1 emits kf8, ==2 emits vf8 (OCP e4m3 shadows).
// ---------------------------------------------------------------------------
__global__ __launch_bounds__(256) void proj_gemm(
    const unsigned short* __restrict__ xb, const unsigned short* __restrict__ Wt,
    const float* __restrict__ bg,
    unsigned short* __restrict__ qb, unsigned short* __restrict__ kb,
    unsigned short* __restrict__ vb, unsigned short* __restrict__ gb,
    unsigned char* __restrict__ kf8, unsigned char* __restrict__ vf8)
{
    const int row0 = blockIdx.x * 128;
    const int col0 = blockIdx.y * 128;      // buffer select
    const int wid  = threadIdx.x >> 6;
    const int lane = threadIdx.x & 63;
    const int wm = wid >> 1, wn = wid & 1;
    const int l15 = lane & 15, lg = lane >> 4;

    f32x4 acc[4][4];
    #pragma unroll
    for (int i = 0; i < 4; ++i)
        #pragma unroll
        for (int j = 0; j < 4; ++j) acc[i][j] = (f32x4){0.f,0.f,0.f,0.f};

    const unsigned short* Ab = xb + ((size_t)(row0 + wm*64 + l15)) * IFZ + lg*8;
    const unsigned short* Bb = Wt + ((size_t)(col0 + wn*64 + l15)) * IFZ + lg*8;

    #pragma unroll
    for (int ks = 0; ks < 4; ++ks) {
        short8v a[4], b[4];
        #pragma unroll
        for (int f = 0; f < 4; ++f) {
            a[f] = *((const short8v*)(Ab + (size_t)f*16*IFZ + ks*32));
            b[f] = *((const short8v*)(Bb + (size_t)f*16*IFZ + ks*32));
        }
        #pragma unroll
        for (int fm = 0; fm < 4; ++fm)
            #pragma unroll
            for (int fn = 0; fn < 4; ++fn)
                acc[fm][fn] = __builtin_amdgcn_mfma_f32_16x16x32_bf16(
                    b[fn], a[fm], acc[fm][fn], 0, 0, 0);   // SWAPPED -> C^T frag
    }

    unsigned short* ob;
    switch (blockIdx.y) { case 0: ob = qb; break; case 1: ob = kb; break;
                          case 2: ob = vb; break; default: ob = gb; break; }
    const bool gate = (blockIdx.y == 3);
    unsigned char* f8 = (blockIdx.y == 1) ? kf8 : (blockIdx.y == 2) ? vf8 : (unsigned char*)0;

    #pragma unroll
    for (int fm = 0; fm < 4; ++fm) {
        const int row = row0 + wm*64 + fm*16 + l15;
        unsigned short* rp = ob + (size_t)row * IFZ;
        #pragma unroll
        for (int fn = 0; fn < 4; ++fn) {
            const int cbase = wn*64 + fn*16 + lg*4;
            float v0 = acc[fm][fn][0], v1 = acc[fm][fn][1];
            float v2 = acc[fm][fn][2], v3 = acc[fm][fn][3];
            if (gate) {
                const float4 bg4 = *(const float4*)(bg + cbase);
                v0 = 1.f/(1.f + __expf(-(v0 + bg4.x)));
                v1 = 1.f/(1.f + __expf(-(v1 + bg4.y)));
                v2 = 1.f/(1.f + __expf(-(v2 + bg4.z)));
                v3 = 1.f/(1.f + __expf(-(v3 + bg4.w)));
            }
            uint2 o;
            o.x = pack2(v0, v1);
            o.y = pack2(v2, v3);
            *(uint2*)(rp + cbase) = o;
            if (f8) {
                int p = __builtin_amdgcn_cvt_pk_fp8_f32(v0, v1, 0, false);
                p     = __builtin_amdgcn_cvt_pk_fp8_f32(v2, v3, p, true);
                *(unsigned*)(f8 + (size_t)row*128 + cbase) = (unsigned)p;
            }
        }
    }
}

// ---------------------------------------------------------------------------
// attn: neighbor K scores from kf8; neighbor V context from vf8; self-V
// direct from global (no vsu staging -> ~25 KB LDS, 6 blocks/CU).
// ---------------------------------------------------------------------------
__global__ __launch_bounds__(256) void attn_kernel(
    const unsigned short* __restrict__ qb, const unsigned short* __restrict__ kb,
    const unsigned short* __restrict__ vb, const unsigned short* __restrict__ gb,
    const float* __restrict__ bbuf, const int* __restrict__ edge,
    const unsigned char* __restrict__ kf8, const unsigned char* __restrict__ vf8,
    unsigned short* __restrict__ obuf)
{
    const int n   = blockIdx.x;
    const int tid = threadIdx.x;

    __shared__ unsigned qsu[KZ*68];      // [kk][a][17] packed bf16 pairs
    __shared__ unsigned ksu[KZ*68];
    __shared__ float    sc[KZ][AHZ][41];
    __shared__ float    bs[KZ*AHZ];
    __shared__ int      es[KZ];

    const size_t base  = (size_t)n * (KZ*IFZ);
    const size_t base2 = base >> 1;              // uint index

    {
        const uint4* qsrc = (const uint4*)(qb + base);
        const uint4* ksrc = (const uint4*)(kb + base);
        for (int i = tid; i < KZ*16; i += 256) {
            const int r = i >> 4, u4 = i & 15;
            const int d = r*68 + (u4 >> 2)*17 + (u4 & 3)*4;
            uint4 v;
            v = qsrc[i]; qsu[d]=v.x; qsu[d+1]=v.y; qsu[d+2]=v.z; qsu[d+3]=v.w;
            v = ksrc[i]; ksu[d]=v.x; ksu[d+1]=v.y; ksu[d+2]=v.z; ksu[d+3]=v.w;
        }
    }
    if (tid < KZ)      es[tid] = edge[n*KZ + tid];
    if (tid < KZ*AHZ)  bs[tid] = bbuf[(size_t)n*(KZ*AHZ) + tid];
    __syncthreads();

    const float rscale = 0.17677669529663687f;  // 1/sqrt(32)

    // Phase 1a: self scores. it = kk*80 + j*4 + a (1600 items)
    for (int it = tid; it < KZ*KZ*AHZ; it += 256) {
        const int a  = it & 3;
        const int j  = (it >> 2) % KZ;
        const int kk = it / (KZ*AHZ);
        const unsigned* qrow = &qsu[kk*68 + a*17];
        const unsigned* krow = &ksu[j*68 + a*17];
        float s = 0.f;
        #pragma unroll
        for (int c2 = 0; c2 < 16; ++c2) {
            const unsigned qu = qrow[c2], ku = krow[c2];
            s += blo(qu)*blo(ku) + bhi(qu)*bhi(ku);
        }
        sc[kk][a][j] = s*rscale + bs[j*AHZ + a];
    }

    // Phase 1b: neighbor scores from kf8. it = kk*80 + jj*4 + a (1600 items)
    for (int it = tid; it < KZ*KZ*AHZ; it += 256) {
        const int a  = it & 3;
        const int jj = (it >> 2) % KZ;
        const int kk = it / (KZ*AHZ);
        const int e  = es[kk];
        const unsigned* qrow = &qsu[kk*68 + a*17];
        const unsigned char* kp = kf8 + ((size_t)e*KZ + jj)*128 + a*32;
        const uint4 k1 = *(const uint4*)kp;
        const uint4 k2 = *(const uint4*)(kp + 16);
        float s = 0.f;
        unsigned ks_[8] = {k1.x, k1.y, k1.z, k1.w, k2.x, k2.y, k2.z, k2.w};
        #pragma unroll
        for (int u = 0; u < 8; ++u) {
            const f32x2 lo = __builtin_amdgcn_cvt_pk_f32_fp8(ks_[u], false);
            const f32x2 hi = __builtin_amdgcn_cvt_pk_f32_fp8(ks_[u], true);
            const unsigned q0 = qrow[2*u], q1 = qrow[2*u+1];
            s += blo(q0)*lo.x + bhi(q0)*lo.y + blo(q1)*hi.x + bhi(q1)*hi.y;
        }
        sc[kk][a][KZ + jj] = s*rscale + bbuf[((size_t)e*KZ + jj)*AHZ + a];
    }
    __syncthreads();

    // Phase 2: softmax over the 40 keys, one thread per (kk,a) row.
    if (tid < KZ*AHZ) {
        const int kk = tid >> 2, a = tid & 3;
        float* row = &sc[kk][a][0];
        float m = row[0];
        #pragma unroll
        for (int j = 1; j < TWO_KZ; ++j) m = fmaxf(m, row[j]);
        float ssum = 0.f;
        #pragma unroll
        for (int j = 0; j < TWO_KZ; ++j) { const float e = __expf(row[j]-m); row[j] = e; ssum += e; }
        const float inv = 1.f/ssum;
        #pragma unroll
        for (int j = 0; j < TWO_KZ; ++j) row[j] *= inv;
    }
    __syncthreads();

    // Phase 3: context + gate, column pairs. it = kk*64 + c2 (1280 items)
    for (int it = tid; it < KZ*64; it += 256) {
        const int kk = it >> 6;
        const int c2 = it & 63;          // column pair: cols {2c2, 2c2+1}
        const int a  = c2 >> 4;
        const float* wrow = &sc[kk][a][0];
        float acc0 = 0.f, acc1 = 0.f;
        const unsigned* vbu = (const unsigned*)vb;
        #pragma unroll
        for (int j = 0; j < KZ; ++j) {
            const unsigned u = vbu[base2 + j*64 + c2];
            const float w = wrow[j];
            acc0 += w*blo(u); acc1 += w*bhi(u);
        }
        const int e = es[kk];
        const unsigned char* vp = vf8 + ((size_t)e*KZ)*128 + c2*2;
        #pragma unroll
        for (int j = 0; j < KZ; ++j) {
            const unsigned u = *(const unsigned short*)(vp + j*128);
            const f32x2 v2 = __builtin_amdgcn_cvt_pk_f32_fp8(u, false);
            const float w = wrow[KZ + j];
            acc0 += w*v2.x; acc1 += w*v2.y;
        }
        const unsigned gu = ((const unsigned*)gb)[base2 + it];
        const float o0 = acc0 * blo(gu);
        const float o1 = acc1 * bhi(gu);
        ((unsigned*)obuf)[base2 + it] = pack2(o0, o1);
    }
}

// ---------------------------------------------------------------------------
// back_ln: y = ob @ Wbt^T + bback + sqrt2*x, then LayerNorm. MFMA, BM=64.
// ---------------------------------------------------------------------------
__global__ __launch_bounds__(256) void back_ln_kernel(
    const unsigned short* __restrict__ ob, const unsigned short* __restrict__ Wbt,
    const float* __restrict__ x, const float* __restrict__ bback,
    const float* __restrict__ gamma, const float* __restrict__ beta,
    float* __restrict__ out)
{
    __shared__ float ys[64][132];
    __shared__ float st[64][2];
    const int row0 = blockIdx.x * 64;
    const int tid  = threadIdx.x;
    const int wid  = tid >> 6;
    const int lane = tid & 63;
    const int wm = wid >> 1, wn = wid & 1;
    const int l15 = lane & 15, lg = lane >> 4;

    f32x4 acc[2][4];
    #pragma unroll
    for (int i = 0; i < 2; ++i)
        #pragma unroll
        for (int j = 0; j < 4; ++j) acc[i][j] = (f32x4){0.f,0.f,0.f,0.f};

    const unsigned short* Ab = ob  + ((size_t)(row0 + wm*32 + l15)) * IFZ + lg*8;
    const unsigned short* Bb = Wbt + ((size_t)(wn*64 + l15)) * IFZ + lg*8;

    #pragma unroll
    for (int ksI = 0; ksI < 4; ++ksI) {
        short8v a[2], b[4];
        #pragma unroll
        for (int f = 0; f < 2; ++f) a[f] = *((const short8v*)(Ab + (size_t)f*16*IFZ + ksI*32));
        #pragma unroll
        for (int f = 0; f < 4; ++f) b[f] = *((const short8v*)(Bb + (size_t)f*16*IFZ + ksI*32));
        #pragma unroll
        for (int fm = 0; fm < 2; ++fm)
            #pragma unroll
            for (int fn = 0; fn < 4; ++fn)
                acc[fm][fn] = __builtin_amdgcn_mfma_f32_16x16x32_bf16(
                    a[fm], b[fn], acc[fm][fn], 0, 0, 0);
    }

    const float SQ2 = 1.4142135623730951f;
    #pragma unroll
    for (int fm = 0; fm < 2; ++fm)
        #pragma unroll
        for (int fn = 0; fn < 4; ++fn)
            #pragma unroll
            for (int j = 0; j < 4; ++j) {
                const int rl  = wm*32 + fm*16 + lg*4 + j;
                const int col = wn*64 + fn*16 + l15;
                ys[rl][col] = acc[fm][fn][j] + bback[col]
                            + SQ2 * x[((size_t)(row0 + rl)) * IFZ + col];
            }
    __syncthreads();

    {
        const int row = tid >> 2, q = tid & 3;
        float s1 = 0.f, s2 = 0.f;
        #pragma unroll
        for (int i = 0; i < 32; ++i) {
            const float yv = ys[row][q*32 + i];
            s1 += yv; s2 += yv*yv;
        }
        s1 += __shfl_xor(s1, 1); s2 += __shfl_xor(s2, 1);
        s1 += __shfl_xor(s1, 2); s2 += __shfl_xor(s2, 2);
        if (q == 0) {
            const float mean = s1 * (1.f/IFZ);
            const float var  = s2 * (1.f/IFZ) - mean*mean;
            st[row][0] = mean;
            st[row][1] = rsqrtf(var + 1e-5f);
        }
    }
    __syncthreads();

    {
        const int row = tid >> 2, q = tid & 3;
        const float mean = st[row][0], rstd = st[row][1];
        const float4* gmv = (const float4*)(gamma + q*32);
        const float4* btv = (const float4*)(beta  + q*32);
        float4* ov = (float4*)(out + ((size_t)(row0 + row)) * IFZ + q*32);
        #pragma unroll
        for (int i8 = 0; i8 < 8; ++i8) {
            const float4 g4 = gmv[i8], b4 = btv[i8];
            const float4 yv = *(const float4*)&ys[row][q*32 + i8*4];
            float4 r;
            r.x = g4.x*(yv.x-mean)*rstd + b4.x;
            r.y = g4.y*(yv.y-mean)*rstd + b4.y;
            r.z = g4.z*(yv.z-mean)*rstd + b4.z;
            r.w = g4.w*(yv.w-mean)*rstd + b4.w;
            ov[i8] = r;
        }
    }
}

// ---------------------------------------------------------------------------
extern "C" void kernel_launch(void* const* d_in, const int* in_sizes, int n_in,
                              void* d_out, int out_size, void* d_ws, size_t ws_size,
                              hipStream_t stream) {
    const float* x     = (const float*)d_in[0];
    const int*   edge  = (const int*)  d_in[1];
    const float* Wq    = (const float*)d_in[2];
    const float* Wk    = (const float*)d_in[3];
    const float* Wv    = (const float*)d_in[4];
    const float* Wb    = (const float*)d_in[5];
    const float* Wg    = (const float*)d_in[6];
    const float* bg    = (const float*)d_in[7];
    const float* Wback = (const float*)d_in[8];
    const float* bback = (const float*)d_in[9];
    const float* gamma = (const float*)d_in[10];
    const float* beta  = (const float*)d_in[11];
    float* out = (float*)d_out;

    const size_t RE = (size_t)ROWS * IFZ;   // 5,242,880 elements
    unsigned short* qb  = (unsigned short*)d_ws;
    unsigned short* kb  = qb + RE;
    unsigned short* vb  = kb + RE;
    unsigned short* gb  = vb + RE;
    unsigned short* obuf= gb + RE;
    unsigned short* xb  = obuf + RE;
    unsigned short* Wt  = xb + RE;          // 512*128
    unsigned short* Wbt = Wt + 512*128;     // 128*128
    float*          bbuf= (float*)(Wbt + 128*128);   // ROWS*4 f32
    unsigned char*  kf8 = (unsigned char*)(bbuf + (size_t)ROWS*4);  // ROWS*128 B
    unsigned char*  vf8 = kf8 + RE;                                  // ROWS*128 B
    // total ws use ~74 MB

    setup_kernel<<<3040, 256, 0, stream>>>(x, Wq, Wk, Wv, Wg, Wback, Wb,
                                           xb, Wt, Wbt, bbuf);
    proj_gemm  <<<dim3(ROWS/128, 4), 256, 0, stream>>>(xb, Wt, bg, qb, kb, vb, gb, kf8, vf8);
    attn_kernel<<<NN, 256, 0, stream>>>(qb, kb, vb, gb, bbuf, edge, kf8, vf8, obuf);
    back_ln_kernel<<<ROWS/64, 256, 0, stream>>>(obuf, Wbt, x, bback, gamma, beta, out);
}

// Round 10
// 120.642 us; speedup vs baseline: 1.3389x; 1.0272x over previous
//
#include <hip/hip_runtime.h>
#include <math.h>

#define NN   2048
#define KZ   20
#define IFZ  128
#define AHZ  4
#define AFZ  32
#define ROWS (NN*KZ)           // 40960
#define TWO_KZ (2*KZ)          // 40

typedef __attribute__((ext_vector_type(8))) short short8v;   // 8 bf16 = 4 VGPR
typedef __attribute__((ext_vector_type(4))) float f32x4;     // MFMA acc
typedef __attribute__((ext_vector_type(2))) float f32x2;

__device__ __forceinline__ float blo(unsigned int u) {      // low bf16 of packed pair
    union { unsigned int i; float f; } x; x.i = u << 16; return x.f;
}
__device__ __forceinline__ float bhi(unsigned int u) {      // high bf16 of packed pair
    union { unsigned int i; float f; } x; x.i = u & 0xffff0000u; return x.f;
}
__device__ __forceinline__ unsigned short f2b(float f) {
    union { float f; unsigned int i; } x; x.f = f;
    unsigned int r = x.i + 0x7fffu + ((x.i >> 16) & 1u);
    return (unsigned short)(r >> 16);
}
__device__ __forceinline__ unsigned pack2(float a, float b) {
    return (unsigned)f2b(a) | ((unsigned)f2b(b) << 16);
}

// ---------------------------------------------------------------------------
// setup: fused prep_x (blocks 0..2559) | wtrans (2560..2879) | bproj f32
// (2880..3039).
// ---------------------------------------------------------------------------
__global__ __launch_bounds__(256) void setup_kernel(
    const float* __restrict__ x,
    const float* __restrict__ Wq, const float* __restrict__ Wk,
    const float* __restrict__ Wv, const float* __restrict__ Wg,
    const float* __restrict__ Wback, const float* __restrict__ Wb,
    unsigned short* __restrict__ xb, unsigned short* __restrict__ Wt,
    unsigned short* __restrict__ Wbt, float* __restrict__ bbuf)
{
    const int b   = blockIdx.x;
    const int tid = threadIdx.x;

    if (b < 2560) {                       // ---- prep_x: 8 elems/thread
        const int gid = b * 256 + tid;
        const float4* src = (const float4*)x;
        float4 v0 = src[gid * 2];
        float4 v1 = src[gid * 2 + 1];
        uint4 o;
        o.x = pack2(v0.x, v0.y);
        o.y = pack2(v0.z, v0.w);
        o.z = pack2(v1.x, v1.y);
        o.w = pack2(v1.z, v1.w);
        ((uint4*)xb)[gid] = o;
    } else if (b < 2880) {                // ---- wtrans
        const int gid = (b - 2560) * 256 + tid;
        if (gid < 512 * 128) {
            const int n = gid >> 7, k = gid & 127;
            const float* W; int c;
            if      (n < 128) { W = Wq; c = n; }
            else if (n < 256) { W = Wk; c = n - 128; }
            else if (n < 384) { W = Wv; c = n - 256; }
            else              { W = Wg; c = n - 384; }
            Wt[gid] = f2b(W[k * 128 + c]);
        } else {
            const int g2 = gid - 512 * 128;
            const int n = g2 >> 7, k = g2 & 127;
            Wbt[g2] = f2b(Wback[k * 128 + n]);
        }
    } else {                              // ---- bproj (f32 x)
        const int row = (b - 2880) * 256 + tid;
        const float4* xv = (const float4*)(x + (size_t)row * IFZ);
        const float4* wv = (const float4*)Wb;
        float4 acc = make_float4(0.f, 0.f, 0.f, 0.f);
        #pragma unroll
        for (int k4 = 0; k4 < 32; ++k4) {
            const float4 xc = xv[k4];
            float4 w;
            w = wv[k4*4+0]; acc.x += xc.x*w.x; acc.y += xc.x*w.y; acc.z += xc.x*w.z; acc.w += xc.x*w.w;
            w = wv[k4*4+1]; acc.x += xc.y*w.x; acc.y += xc.y*w.y; acc.z += xc.y*w.z; acc.w += xc.y*w.w;
            w = wv[k4*4+2]; acc.x += xc.z*w.x; acc.y += xc.z*w.y; acc.z += xc.z*w.z; acc.w += xc.z*w.w;
            w = wv[k4*4+3]; acc.x += xc.w*w.x; acc.y += xc.w*w.y; acc.z += xc.w*w.z; acc.w += xc.w*w.w;
        }
        ((float4*)bbuf)[row] = acc;
    }
}

// ---------------------------------------------------------------------------
// proj_gemm v2: one block per 128-row tile; cc-loop over the 4 col-buffers
// with A fragments held in registers (read once, reused 4x). Swapped MFMA
// operands -> C^T fragment -> packed uint2 stores.
// cc0 -> qb bf16; cc1 -> kb bf16 + kf8; cc2 -> vf8 ONLY; cc3 -> gb (gated).
// ---------------------------------------------------------------------------
__global__ __launch_bounds__(256) void proj_gemm(
    const unsigned short* __restrict__ xb, const unsigned short* __restrict__ Wt,
    const float* __restrict__ bg,
    unsigned short* __restrict__ qb, unsigned short* __restrict__ kb,
    unsigned short* __restrict__ gb,
    unsigned char* __restrict__ kf8, unsigned char* __restrict__ vf8)
{
    const int row0 = blockIdx.x * 128;
    const int wid  = threadIdx.x >> 6;
    const int lane = threadIdx.x & 63;
    const int wm = wid >> 1, wn = wid & 1;
    const int l15 = lane & 15, lg = lane >> 4;

    // A fragments once: a[ks][fm]
    short8v a[4][4];
    {
        const unsigned short* Ab = xb + ((size_t)(row0 + wm*64 + l15)) * IFZ + lg*8;
        #pragma unroll
        for (int ks = 0; ks < 4; ++ks)
            #pragma unroll
            for (int fm = 0; fm < 4; ++fm)
                a[ks][fm] = *((const short8v*)(Ab + (size_t)fm*16*IFZ + ks*32));
    }

    #pragma unroll
    for (int cc = 0; cc < 4; ++cc) {
        const unsigned short* Bb = Wt + ((size_t)(cc*128 + wn*64 + l15)) * IFZ + lg*8;

        f32x4 acc[4][4];
        #pragma unroll
        for (int i = 0; i < 4; ++i)
            #pragma unroll
            for (int j = 0; j < 4; ++j) acc[i][j] = (f32x4){0.f,0.f,0.f,0.f};

        #pragma unroll
        for (int ks = 0; ks < 4; ++ks) {
            short8v b[4];
            #pragma unroll
            for (int f = 0; f < 4; ++f)
                b[f] = *((const short8v*)(Bb + (size_t)f*16*IFZ + ks*32));
            #pragma unroll
            for (int fm = 0; fm < 4; ++fm)
                #pragma unroll
                for (int fn = 0; fn < 4; ++fn)
                    acc[fm][fn] = __builtin_amdgcn_mfma_f32_16x16x32_bf16(
                        b[fn], a[ks][fm], acc[fm][fn], 0, 0, 0);   // SWAPPED
        }

        const bool gate = (cc == 3);
        unsigned short* ob = (cc == 0) ? qb : (cc == 1) ? kb : (cc == 3) ? gb : (unsigned short*)0;
        unsigned char*  f8 = (cc == 1) ? kf8 : (cc == 2) ? vf8 : (unsigned char*)0;

        #pragma unroll
        for (int fm = 0; fm < 4; ++fm) {
            const int row = row0 + wm*64 + fm*16 + l15;
            #pragma unroll
            for (int fn = 0; fn < 4; ++fn) {
                const int cbase = wn*64 + fn*16 + lg*4;
                float v0 = acc[fm][fn][0], v1 = acc[fm][fn][1];
                float v2 = acc[fm][fn][2], v3 = acc[fm][fn][3];
                if (gate) {
                    const float4 bg4 = *(const float4*)(bg + cbase);
                    v0 = 1.f/(1.f + __expf(-(v0 + bg4.x)));
                    v1 = 1.f/(1.f + __expf(-(v1 + bg4.y)));
                    v2 = 1.f/(1.f + __expf(-(v2 + bg4.z)));
                    v3 = 1.f/(1.f + __expf(-(v3 + bg4.w)));
                }
                if (ob) {
                    uint2 o;
                    o.x = pack2(v0, v1);
                    o.y = pack2(v2, v3);
                    *(uint2*)(ob + (size_t)row * IFZ + cbase) = o;
                }
                if (f8) {
                    int p = __builtin_amdgcn_cvt_pk_fp8_f32(v0, v1, 0, false);
                    p     = __builtin_amdgcn_cvt_pk_fp8_f32(v2, v3, p, true);
                    *(unsigned*)(f8 + (size_t)row*128 + cbase) = (unsigned)p;
                }
            }
        }
    }
}

// ---------------------------------------------------------------------------
// attn v5: phase1 thread-owns-(kk,a) with q in f32 regs (3-way j split);
// self-K bf16 LDS, neighbor-K kf8; phase3 all-V from vf8 (self+neighbor),
// self-V ushorts hoisted across 5 kk. LDS ~26.3 KB (layout [kk][a][20]).
// ---------------------------------------------------------------------------
__global__ __launch_bounds__(256) void attn_kernel(
    const unsigned short* __restrict__ qb, const unsigned short* __restrict__ kb,
    const unsigned short* __restrict__ gb,
    const float* __restrict__ bbuf, const int* __restrict__ edge,
    const unsigned char* __restrict__ kf8, const unsigned char* __restrict__ vf8,
    unsigned short* __restrict__ obuf)
{
    const int n   = blockIdx.x;
    const int tid = threadIdx.x;

    __shared__ unsigned qsu[KZ*80];      // [kk][a][20] packed bf16 pairs
    __shared__ unsigned ksu[KZ*80];
    __shared__ float    sc[KZ][AHZ][41];
    __shared__ float    bs[KZ*AHZ];
    __shared__ int      es[KZ];

    const size_t base  = (size_t)n * (KZ*IFZ);
    const size_t base2 = base >> 1;              // uint index

    {
        const uint4* qsrc = (const uint4*)(qb + base);
        const uint4* ksrc = (const uint4*)(kb + base);
        for (int i = tid; i < KZ*16; i += 256) {
            const int r = i >> 4, u4 = i & 15;
            const int d = r*80 + (u4 >> 2)*20 + (u4 & 3)*4;
            *(uint4*)&qsu[d] = qsrc[i];
            *(uint4*)&ksu[d] = ksrc[i];
        }
    }
    if (tid < KZ)      es[tid] = edge[n*KZ + tid];
    if (tid < KZ*AHZ)  bs[tid] = bbuf[(size_t)n*(KZ*AHZ) + tid];
    __syncthreads();

    const float rscale = 0.17677669529663687f;  // 1/sqrt(32)

    // ---- Phase 1: thread t<240 owns pair p=t/3 (kk=p>>2, a=p&3), part r3.
    if (tid < 240) {
        const int p  = tid / 3, r3 = tid - p*3;
        const int kk = p >> 2, a = p & 3;

        // q row -> f32 registers (unpack once)
        float qf[32];
        {
            const uint4 q0 = *(const uint4*)&qsu[kk*80 + a*20 + 0];
            const uint4 q1 = *(const uint4*)&qsu[kk*80 + a*20 + 4];
            const uint4 q2 = *(const uint4*)&qsu[kk*80 + a*20 + 8];
            const uint4 q3 = *(const uint4*)&qsu[kk*80 + a*20 + 12];
            unsigned qu_[16] = {q0.x,q0.y,q0.z,q0.w, q1.x,q1.y,q1.z,q1.w,
                                q2.x,q2.y,q2.z,q2.w, q3.x,q3.y,q3.z,q3.w};
            #pragma unroll
            for (int c = 0; c < 16; ++c) { qf[2*c] = blo(qu_[c]); qf[2*c+1] = bhi(qu_[c]); }
        }

        // self keys (bf16 LDS)
        for (int j = r3; j < KZ; j += 3) {
            const int kbse = j*80 + a*20;
            const uint4 k0 = *(const uint4*)&ksu[kbse + 0];
            const uint4 k1 = *(const uint4*)&ksu[kbse + 4];
            const uint4 k2 = *(const uint4*)&ksu[kbse + 8];
            const uint4 k3 = *(const uint4*)&ksu[kbse + 12];
            unsigned ku_[16] = {k0.x,k0.y,k0.z,k0.w, k1.x,k1.y,k1.z,k1.w,
                                k2.x,k2.y,k2.z,k2.w, k3.x,k3.y,k3.z,k3.w};
            float s = 0.f;
            #pragma unroll
            for (int c = 0; c < 16; ++c)
                s += qf[2*c]*blo(ku_[c]) + qf[2*c+1]*bhi(ku_[c]);
            sc[kk][a][j] = s*rscale + bs[j*AHZ + a];
        }

        // neighbor keys (fp8)
        {
            const int e = es[kk];
            for (int jj = r3; jj < KZ; jj += 3) {
                const unsigned char* kp = kf8 + ((size_t)e*KZ + jj)*128 + a*32;
                const uint4 k1 = *(const uint4*)kp;
                const uint4 k2 = *(const uint4*)(kp + 16);
                unsigned ks_[8] = {k1.x, k1.y, k1.z, k1.w, k2.x, k2.y, k2.z, k2.w};
                float s = 0.f;
                #pragma unroll
                for (int u = 0; u < 8; ++u) {
                    const f32x2 lo = __builtin_amdgcn_cvt_pk_f32_fp8(ks_[u], false);
                    const f32x2 hi = __builtin_amdgcn_cvt_pk_f32_fp8(ks_[u], true);
                    s += qf[4*u]*lo.x + qf[4*u+1]*lo.y + qf[4*u+2]*hi.x + qf[4*u+3]*hi.y;
                }
                sc[kk][a][KZ + jj] = s*rscale + bbuf[((size_t)e*KZ + jj)*AHZ + a];
            }
        }
    }
    __syncthreads();

    // ---- Phase 2: softmax over the 40 keys, one thread per (kk,a) row.
    if (tid < KZ*AHZ) {
        const int kk = tid >> 2, a = tid & 3;
        float* row = &sc[kk][a][0];
        float m = row[0];
        #pragma unroll
        for (int j = 1; j < TWO_KZ; ++j) m = fmaxf(m, row[j]);
        float ssum = 0.f;
        #pragma unroll
        for (int j = 0; j < TWO_KZ; ++j) { const float e = __expf(row[j]-m); row[j] = e; ssum += e; }
        const float inv = 1.f/ssum;
        #pragma unroll
        for (int j = 0; j < TWO_KZ; ++j) row[j] *= inv;
    }
    __syncthreads();

    // ---- Phase 3: thread = (kkg=tid>>6, c2=tid&63); V entirely from vf8.
    {
        const int kkg = tid >> 6;
        const int c2  = tid & 63;
        const int a   = c2 >> 4;

        // self-V column pair (fp8 ushorts) hoisted into regs, reused for 5 kk
        unsigned vs_[KZ];
        {
            const unsigned char* vself = vf8 + (size_t)n*(KZ*128) + c2*2;
            #pragma unroll
            for (int j = 0; j < KZ; ++j)
                vs_[j] = *(const unsigned short*)(vself + j*128);
        }

        const unsigned* gbu = (const unsigned*)gb;
        unsigned* obu = (unsigned*)obuf;

        #pragma unroll
        for (int i = 0; i < 5; ++i) {
            const int kk = kkg*5 + i;
            const float* wrow = &sc[kk][a][0];
            float acc0 = 0.f, acc1 = 0.f;
            #pragma unroll
            for (int j = 0; j < KZ; ++j) {
                const f32x2 v2 = __builtin_amdgcn_cvt_pk_f32_fp8(vs_[j], false);
                const float w = wrow[j];
                acc0 += w*v2.x; acc1 += w*v2.y;
            }
            const unsigned char* vnb = vf8 + (size_t)es[kk]*(KZ*128) + c2*2;
            #pragma unroll
            for (int j = 0; j < KZ; ++j) {
                const unsigned u = *(const unsigned short*)(vnb + j*128);
                const f32x2 v2 = __builtin_amdgcn_cvt_pk_f32_fp8(u, false);
                const float w = wrow[KZ + j];
                acc0 += w*v2.x; acc1 += w*v2.y;
            }
            const unsigned gu = gbu[base2 + kk*64 + c2];
            const float o0 = acc0 * blo(gu);
            const float o1 = acc1 * bhi(gu);
            obu[base2 + kk*64 + c2] = pack2(o0, o1);
        }
    }
}

// ---------------------------------------------------------------------------
// back_ln: y = ob @ Wbt^T + bback + sqrt2*x, then LayerNorm. MFMA, BM=64.
// ---------------------------------------------------------------------------
__global__ __launch_bounds__(256) void back_ln_kernel(
    const unsigned short* __restrict__ ob, const unsigned short* __restrict__ Wbt,
    const float* __restrict__ x, const float* __restrict__ bback,
    const float* __restrict__ gamma, const float* __restrict__ beta,
    float* __restrict__ out)
{
    __shared__ float ys[64][132];
    __shared__ float st[64][2];
    const int row0 = blockIdx.x * 64;
    const int tid  = threadIdx.x;
    const int wid  = tid >> 6;
    const int lane = tid & 63;
    const int wm = wid >> 1, wn = wid & 1;
    const int l15 = lane & 15, lg = lane >> 4;

    f32x4 acc[2][4];
    #pragma unroll
    for (int i = 0; i < 2; ++i)
        #pragma unroll
        for (int j = 0; j < 4; ++j) acc[i][j] = (f32x4){0.f,0.f,0.f,0.f};

    const unsigned short* Ab = ob  + ((size_t)(row0 + wm*32 + l15)) * IFZ + lg*8;
    const unsigned short* Bb = Wbt + ((size_t)(wn*64 + l15)) * IFZ + lg*8;

    #pragma unroll
    for (int ksI = 0; ksI < 4; ++ksI) {
        short8v a[2], b[4];
        #pragma unroll
        for (int f = 0; f < 2; ++f) a[f] = *((const short8v*)(Ab + (size_t)f*16*IFZ + ksI*32));
        #pragma unroll
        for (int f = 0; f < 4; ++f) b[f] = *((const short8v*)(Bb + (size_t)f*16*IFZ + ksI*32));
        #pragma unroll
        for (int fm = 0; fm < 2; ++fm)
            #pragma unroll
            for (int fn = 0; fn < 4; ++fn)
                acc[fm][fn] = __builtin_amdgcn_mfma_f32_16x16x32_bf16(
                    a[fm], b[fn], acc[fm][fn], 0, 0, 0);
    }

    const float SQ2 = 1.4142135623730951f;
    #pragma unroll
    for (int fm = 0; fm < 2; ++fm)
        #pragma unroll
        for (int fn = 0; fn < 4; ++fn)
            #pragma unroll
            for (int j = 0; j < 4; ++j) {
                const int rl  = wm*32 + fm*16 + lg*4 + j;
                const int col = wn*64 + fn*16 + l15;
                ys[rl][col] = acc[fm][fn][j] + bback[col]
                            + SQ2 * x[((size_t)(row0 + rl)) * IFZ + col];
            }
    __syncthreads();

    {
        const int row = tid >> 2, q = tid & 3;
        float s1 = 0.f, s2 = 0.f;
        #pragma unroll
        for (int i = 0; i < 32; ++i) {
            const float yv = ys[row][q*32 + i];
            s1 += yv; s2 += yv*yv;
        }
        s1 += __shfl_xor(s1, 1); s2 += __shfl_xor(s2, 1);
        s1 += __shfl_xor(s1, 2); s2 += __shfl_xor(s2, 2);
        if (q == 0) {
            const float mean = s1 * (1.f/IFZ);
            const float var  = s2 * (1.f/IFZ) - mean*mean;
            st[row][0] = mean;
            st[row][1] = rsqrtf(var + 1e-5f);
        }
    }
    __syncthreads();

    {
        const int row = tid >> 2, q = tid & 3;
        const float mean = st[row][0], rstd = st[row][1];
        const float4* gmv = (const float4*)(gamma + q*32);
        const float4* btv = (const float4*)(beta  + q*32);
        float4* ov = (float4*)(out + ((size_t)(row0 + row)) * IFZ + q*32);
        #pragma unroll
        for (int i8 = 0; i8 < 8; ++i8) {
            const float4 g4 = gmv[i8], b4 = btv[i8];
            const float4 yv = *(const float4*)&ys[row][q*32 + i8*4];
            float4 r;
            r.x = g4.x*(yv.x-mean)*rstd + b4.x;
            r.y = g4.y*(yv.y-mean)*rstd + b4.y;
            r.z = g4.z*(yv.z-mean)*rstd + b4.z;
            r.w = g4.w*(yv.w-mean)*rstd + b4.w;
            ov[i8] = r;
        }
    }
}

// ---------------------------------------------------------------------------
extern "C" void kernel_launch(void* const* d_in, const int* in_sizes, int n_in,
                              void* d_out, int out_size, void* d_ws, size_t ws_size,
                              hipStream_t stream) {
    const float* x     = (const float*)d_in[0];
    const int*   edge  = (const int*)  d_in[1];
    const float* Wq    = (const float*)d_in[2];
    const float* Wk    = (const float*)d_in[3];
    const float* Wv    = (const float*)d_in[4];
    const float* Wb    = (const float*)d_in[5];
    const float* Wg    = (const float*)d_in[6];
    const float* bg    = (const float*)d_in[7];
    const float* Wback = (const float*)d_in[8];
    const float* bback = (const float*)d_in[9];
    const float* gamma = (const float*)d_in[10];
    const float* beta  = (const float*)d_in[11];
    float* out = (float*)d_out;

    const size_t RE = (size_t)ROWS * IFZ;   // 5,242,880 elements
    unsigned short* qb  = (unsigned short*)d_ws;
    unsigned short* kb  = qb + RE;
    unsigned short* gb  = kb + RE;
    unsigned short* obuf= gb + RE;
    unsigned short* xb  = obuf + RE;
    unsigned short* Wt  = xb + RE;          // 512*128
    unsigned short* Wbt = Wt + 512*128;     // 128*128
    float*          bbuf= (float*)(Wbt + 128*128);   // ROWS*4 f32
    unsigned char*  kf8 = (unsigned char*)(bbuf + (size_t)ROWS*4);  // ROWS*128 B
    unsigned char*  vf8 = kf8 + RE;                                  // ROWS*128 B
    // total ws use ~63 MB

    setup_kernel<<<3040, 256, 0, stream>>>(x, Wq, Wk, Wv, Wg, Wback, Wb,
                                           xb, Wt, Wbt, bbuf);
    proj_gemm  <<<ROWS/128, 256, 0, stream>>>(xb, Wt, bg, qb, kb, gb, kf8, vf8);
    attn_kernel<<<NN, 256, 0, stream>>>(qb, kb, gb, bbuf, edge, kf8, vf8, obuf);
    back_ln_kernel<<<ROWS/64, 256, 0, stream>>>(obuf, Wbt, x, bback, gamma, beta, out);
}

// Round 11
// 111.078 us; speedup vs baseline: 1.4541x; 1.0861x over previous
//
#include <hip/hip_runtime.h>
#include <math.h>

#define NN   2048
#define KZ   20
#define IFZ  128
#define AHZ  4
#define AFZ  32
#define ROWS (NN*KZ)           // 40960
#define TWO_KZ (2*KZ)          // 40

typedef __attribute__((ext_vector_type(8))) short short8v;   // 8 bf16 = 4 VGPR
typedef __attribute__((ext_vector_type(4))) float f32x4;     // MFMA acc
typedef __attribute__((ext_vector_type(2))) float f32x2;

__device__ __forceinline__ float blo(unsigned int u) {      // low bf16 of packed pair
    union { unsigned int i; float f; } x; x.i = u << 16; return x.f;
}
__device__ __forceinline__ float bhi(unsigned int u) {      // high bf16 of packed pair
    union { unsigned int i; float f; } x; x.i = u & 0xffff0000u; return x.f;
}
__device__ __forceinline__ unsigned short f2b(float f) {
    union { float f; unsigned int i; } x; x.f = f;
    unsigned int r = x.i + 0x7fffu + ((x.i >> 16) & 1u);
    return (unsigned short)(r >> 16);
}
__device__ __forceinline__ unsigned pack2(float a, float b) {
    return (unsigned)f2b(a) | ((unsigned)f2b(b) << 16);
}

// ---------------------------------------------------------------------------
// setup: fused prep_x (blocks 0..2559) | wtrans (2560..2879) | bproj f32
// (2880..3039).
// ---------------------------------------------------------------------------
__global__ __launch_bounds__(256) void setup_kernel(
    const float* __restrict__ x,
    const float* __restrict__ Wq, const float* __restrict__ Wk,
    const float* __restrict__ Wv, const float* __restrict__ Wg,
    const float* __restrict__ Wback, const float* __restrict__ Wb,
    unsigned short* __restrict__ xb, unsigned short* __restrict__ Wt,
    unsigned short* __restrict__ Wbt, float* __restrict__ bbuf)
{
    const int b   = blockIdx.x;
    const int tid = threadIdx.x;

    if (b < 2560) {                       // ---- prep_x: 8 elems/thread
        const int gid = b * 256 + tid;
        const float4* src = (const float4*)x;
        float4 v0 = src[gid * 2];
        float4 v1 = src[gid * 2 + 1];
        uint4 o;
        o.x = pack2(v0.x, v0.y);
        o.y = pack2(v0.z, v0.w);
        o.z = pack2(v1.x, v1.y);
        o.w = pack2(v1.z, v1.w);
        ((uint4*)xb)[gid] = o;
    } else if (b < 2880) {                // ---- wtrans
        const int gid = (b - 2560) * 256 + tid;
        if (gid < 512 * 128) {
            const int n = gid >> 7, k = gid & 127;
            const float* W; int c;
            if      (n < 128) { W = Wq; c = n; }
            else if (n < 256) { W = Wk; c = n - 128; }
            else if (n < 384) { W = Wv; c = n - 256; }
            else              { W = Wg; c = n - 384; }
            Wt[gid] = f2b(W[k * 128 + c]);
        } else {
            const int g2 = gid - 512 * 128;
            const int n = g2 >> 7, k = g2 & 127;
            Wbt[g2] = f2b(Wback[k * 128 + n]);
        }
    } else {                              // ---- bproj (f32 x)
        const int row = (b - 2880) * 256 + tid;
        const float4* xv = (const float4*)(x + (size_t)row * IFZ);
        const float4* wv = (const float4*)Wb;
        float4 acc = make_float4(0.f, 0.f, 0.f, 0.f);
        #pragma unroll
        for (int k4 = 0; k4 < 32; ++k4) {
            const float4 xc = xv[k4];
            float4 w;
            w = wv[k4*4+0]; acc.x += xc.x*w.x; acc.y += xc.x*w.y; acc.z += xc.x*w.z; acc.w += xc.x*w.w;
            w = wv[k4*4+1]; acc.x += xc.y*w.x; acc.y += xc.y*w.y; acc.z += xc.y*w.z; acc.w += xc.y*w.w;
            w = wv[k4*4+2]; acc.x += xc.z*w.x; acc.y += xc.z*w.y; acc.z += xc.z*w.z; acc.w += xc.z*w.w;
            w = wv[k4*4+3]; acc.x += xc.w*w.x; acc.y += xc.w*w.y; acc.z += xc.w*w.z; acc.w += xc.w*w.w;
        }
        ((float4*)bbuf)[row] = acc;
    }
}

// ---------------------------------------------------------------------------
// proj_gemm v2: one block per 128-row tile; cc-loop over the 4 col-buffers
// with A fragments held in registers. Swapped MFMA -> C^T frag -> uint2 stores.
// cc0 -> qb bf16; cc1 -> kb bf16 + kf8; cc2 -> vf8 ONLY; cc3 -> gb (gated).
// ---------------------------------------------------------------------------
__global__ __launch_bounds__(256) void proj_gemm(
    const unsigned short* __restrict__ xb, const unsigned short* __restrict__ Wt,
    const float* __restrict__ bg,
    unsigned short* __restrict__ qb, unsigned short* __restrict__ kb,
    unsigned short* __restrict__ gb,
    unsigned char* __restrict__ kf8, unsigned char* __restrict__ vf8)
{
    const int row0 = blockIdx.x * 128;
    const int wid  = threadIdx.x >> 6;
    const int lane = threadIdx.x & 63;
    const int wm = wid >> 1, wn = wid & 1;
    const int l15 = lane & 15, lg = lane >> 4;

    short8v a[4][4];
    {
        const unsigned short* Ab = xb + ((size_t)(row0 + wm*64 + l15)) * IFZ + lg*8;
        #pragma unroll
        for (int ks = 0; ks < 4; ++ks)
            #pragma unroll
            for (int fm = 0; fm < 4; ++fm)
                a[ks][fm] = *((const short8v*)(Ab + (size_t)fm*16*IFZ + ks*32));
    }

    #pragma unroll
    for (int cc = 0; cc < 4; ++cc) {
        const unsigned short* Bb = Wt + ((size_t)(cc*128 + wn*64 + l15)) * IFZ + lg*8;

        f32x4 acc[4][4];
        #pragma unroll
        for (int i = 0; i < 4; ++i)
            #pragma unroll
            for (int j = 0; j < 4; ++j) acc[i][j] = (f32x4){0.f,0.f,0.f,0.f};

        #pragma unroll
        for (int ks = 0; ks < 4; ++ks) {
            short8v b[4];
            #pragma unroll
            for (int f = 0; f < 4; ++f)
                b[f] = *((const short8v*)(Bb + (size_t)f*16*IFZ + ks*32));
            #pragma unroll
            for (int fm = 0; fm < 4; ++fm)
                #pragma unroll
                for (int fn = 0; fn < 4; ++fn)
                    acc[fm][fn] = __builtin_amdgcn_mfma_f32_16x16x32_bf16(
                        b[fn], a[ks][fm], acc[fm][fn], 0, 0, 0);   // SWAPPED
        }

        const bool gate = (cc == 3);
        unsigned short* ob = (cc == 0) ? qb : (cc == 1) ? kb : (cc == 3) ? gb : (unsigned short*)0;
        unsigned char*  f8 = (cc == 1) ? kf8 : (cc == 2) ? vf8 : (unsigned char*)0;

        #pragma unroll
        for (int fm = 0; fm < 4; ++fm) {
            const int row = row0 + wm*64 + fm*16 + l15;
            #pragma unroll
            for (int fn = 0; fn < 4; ++fn) {
                const int cbase = wn*64 + fn*16 + lg*4;
                float v0 = acc[fm][fn][0], v1 = acc[fm][fn][1];
                float v2 = acc[fm][fn][2], v3 = acc[fm][fn][3];
                if (gate) {
                    const float4 bg4 = *(const float4*)(bg + cbase);
                    v0 = 1.f/(1.f + __expf(-(v0 + bg4.x)));
                    v1 = 1.f/(1.f + __expf(-(v1 + bg4.y)));
                    v2 = 1.f/(1.f + __expf(-(v2 + bg4.z)));
                    v3 = 1.f/(1.f + __expf(-(v3 + bg4.w)));
                }
                if (ob) {
                    uint2 o;
                    o.x = pack2(v0, v1);
                    o.y = pack2(v2, v3);
                    *(uint2*)(ob + (size_t)row * IFZ + cbase) = o;
                }
                if (f8) {
                    int p = __builtin_amdgcn_cvt_pk_fp8_f32(v0, v1, 0, false);
                    p     = __builtin_amdgcn_cvt_pk_fp8_f32(v2, v3, p, true);
                    *(unsigned*)(f8 + (size_t)row*128 + cbase) = (unsigned)p;
                }
            }
        }
    }
}

// ---------------------------------------------------------------------------
// attn_back_ln: attention (v5 structure) + fused back-GEMM + residual + LN.
// Block n owns exactly output rows [20n, 20n+20): phase3 writes gated ctx
// (packed bf16) to LDS ctxb (rows 20-31 zeroed); 32x128x128 MFMA back-GEMM
// (Wbt from L2, swapped operands); ys = sqrt2*x + bback init overlaps MFMA;
// add fragments, LN, direct f32 out write. sc LDS reused as ys.
// ---------------------------------------------------------------------------
__global__ __launch_bounds__(256) void attn_back_ln(
    const unsigned short* __restrict__ qb, const unsigned short* __restrict__ kb,
    const unsigned short* __restrict__ gb,
    const float* __restrict__ bbuf, const int* __restrict__ edge,
    const unsigned char* __restrict__ kf8, const unsigned char* __restrict__ vf8,
    const float* __restrict__ x, const unsigned short* __restrict__ Wbt,
    const float* __restrict__ bback, const float* __restrict__ gamma,
    const float* __restrict__ beta, float* __restrict__ out)
{
    const int n   = blockIdx.x;
    const int tid = threadIdx.x;

    __shared__ unsigned qsu[KZ*80];      // [kk][a][20] packed bf16 pairs
    __shared__ unsigned ksu[KZ*80];
    __shared__ float    scys[3280];      // sc (scores) then ys (back+LN), aliased
    __shared__ unsigned ctxb[32*68];     // gated ctx packed bf16; rows 20-31 zero
    __shared__ float    bs[KZ*AHZ];
    __shared__ float    st2[KZ][2];
    __shared__ int      es[KZ];

    const size_t base  = (size_t)n * (KZ*IFZ);
    const size_t base2 = base >> 1;              // uint index

    {
        const uint4* qsrc = (const uint4*)(qb + base);
        const uint4* ksrc = (const uint4*)(kb + base);
        for (int i = tid; i < KZ*16; i += 256) {
            const int r = i >> 4, u4 = i & 15;
            const int d = r*80 + (u4 >> 2)*20 + (u4 & 3)*4;
            *(uint4*)&qsu[d] = qsrc[i];
            *(uint4*)&ksu[d] = ksrc[i];
        }
        for (int i = tid; i < 12*68; i += 256) ctxb[20*68 + i] = 0u;
    }
    if (tid < KZ)      es[tid] = edge[n*KZ + tid];
    if (tid < KZ*AHZ)  bs[tid] = bbuf[(size_t)n*(KZ*AHZ) + tid];
    __syncthreads();

    const float rscale = 0.17677669529663687f;  // 1/sqrt(32)

    // ---- Phase 1: thread t<240 owns pair p=t/3 (kk=p>>2, a=p&3), part r3.
    if (tid < 240) {
        const int p  = tid / 3, r3 = tid - p*3;
        const int kk = p >> 2, a = p & 3;

        float qf[32];
        {
            const uint4 q0 = *(const uint4*)&qsu[kk*80 + a*20 + 0];
            const uint4 q1 = *(const uint4*)&qsu[kk*80 + a*20 + 4];
            const uint4 q2 = *(const uint4*)&qsu[kk*80 + a*20 + 8];
            const uint4 q3 = *(const uint4*)&qsu[kk*80 + a*20 + 12];
            unsigned qu_[16] = {q0.x,q0.y,q0.z,q0.w, q1.x,q1.y,q1.z,q1.w,
                                q2.x,q2.y,q2.z,q2.w, q3.x,q3.y,q3.z,q3.w};
            #pragma unroll
            for (int c = 0; c < 16; ++c) { qf[2*c] = blo(qu_[c]); qf[2*c+1] = bhi(qu_[c]); }
        }

        // self keys (bf16 LDS)
        for (int j = r3; j < KZ; j += 3) {
            const int kbse = j*80 + a*20;
            const uint4 k0 = *(const uint4*)&ksu[kbse + 0];
            const uint4 k1 = *(const uint4*)&ksu[kbse + 4];
            const uint4 k2 = *(const uint4*)&ksu[kbse + 8];
            const uint4 k3 = *(const uint4*)&ksu[kbse + 12];
            unsigned ku_[16] = {k0.x,k0.y,k0.z,k0.w, k1.x,k1.y,k1.z,k1.w,
                                k2.x,k2.y,k2.z,k2.w, k3.x,k3.y,k3.z,k3.w};
            float s = 0.f;
            #pragma unroll
            for (int c = 0; c < 16; ++c)
                s += qf[2*c]*blo(ku_[c]) + qf[2*c+1]*bhi(ku_[c]);
            scys[p*41 + j] = s*rscale + bs[j*AHZ + a];
        }

        // neighbor keys (fp8)
        {
            const int e = es[kk];
            for (int jj = r3; jj < KZ; jj += 3) {
                const unsigned char* kp = kf8 + ((size_t)e*KZ + jj)*128 + a*32;
                const uint4 k1 = *(const uint4*)kp;
                const uint4 k2 = *(const uint4*)(kp + 16);
                unsigned ks_[8] = {k1.x, k1.y, k1.z, k1.w, k2.x, k2.y, k2.z, k2.w};
                float s = 0.f;
                #pragma unroll
                for (int u = 0; u < 8; ++u) {
                    const f32x2 lo = __builtin_amdgcn_cvt_pk_f32_fp8(ks_[u], false);
                    const f32x2 hi = __builtin_amdgcn_cvt_pk_f32_fp8(ks_[u], true);
                    s += qf[4*u]*lo.x + qf[4*u+1]*lo.y + qf[4*u+2]*hi.x + qf[4*u+3]*hi.y;
                }
                scys[p*41 + KZ + jj] = s*rscale + bbuf[((size_t)e*KZ + jj)*AHZ + a];
            }
        }
    }
    __syncthreads();

    // ---- Phase 2: softmax over 40 keys, one thread per (kk,a) row.
    if (tid < KZ*AHZ) {
        float* row = &scys[tid*41];
        float m = row[0];
        #pragma unroll
        for (int j = 1; j < TWO_KZ; ++j) m = fmaxf(m, row[j]);
        float ssum = 0.f;
        #pragma unroll
        for (int j = 0; j < TWO_KZ; ++j) { const float e = __expf(row[j]-m); row[j] = e; ssum += e; }
        const float inv = 1.f/ssum;
        #pragma unroll
        for (int j = 0; j < TWO_KZ; ++j) row[j] *= inv;
    }
    __syncthreads();

    // ---- Phase 3: ctx + gate -> ctxb (LDS). thread = (kkg=tid>>6, c2=tid&63).
    {
        const int kkg = tid >> 6;
        const int c2  = tid & 63;
        const int a   = c2 >> 4;

        unsigned vs_[KZ];
        {
            const unsigned char* vself = vf8 + (size_t)n*(KZ*128) + c2*2;
            #pragma unroll
            for (int j = 0; j < KZ; ++j)
                vs_[j] = *(const unsigned short*)(vself + j*128);
        }

        const unsigned* gbu = (const unsigned*)gb;

        #pragma unroll
        for (int i = 0; i < 5; ++i) {
            const int kk = kkg*5 + i;
            const float* wrow = &scys[(kk*4 + a)*41];
            float acc0 = 0.f, acc1 = 0.f;
            #pragma unroll
            for (int j = 0; j < KZ; ++j) {
                const f32x2 v2 = __builtin_amdgcn_cvt_pk_f32_fp8(vs_[j], false);
                const float w = wrow[j];
                acc0 += w*v2.x; acc1 += w*v2.y;
            }
            const unsigned char* vnb = vf8 + (size_t)es[kk]*(KZ*128) + c2*2;
            #pragma unroll
            for (int j = 0; j < KZ; ++j) {
                const unsigned u = *(const unsigned short*)(vnb + j*128);
                const f32x2 v2 = __builtin_amdgcn_cvt_pk_f32_fp8(u, false);
                const float w = wrow[KZ + j];
                acc0 += w*v2.x; acc1 += w*v2.y;
            }
            const unsigned gu = gbu[base2 + kk*64 + c2];
            ctxb[kk*68 + c2] = pack2(acc0 * blo(gu), acc1 * bhi(gu));
        }
    }
    __syncthreads();     // ctxb ready; scys (scores) dead -> becomes ys

    // ---- Phase 4: back-GEMM compute (MFMA) + ys init (overlapped).
    const int wid  = tid >> 6;
    const int lane = tid & 63;
    const int l15  = lane & 15, lg = lane >> 4;
    const float SQ2 = 1.4142135623730951f;

    f32x4 bacc[2][2];
    #pragma unroll
    for (int i = 0; i < 2; ++i)
        #pragma unroll
        for (int j = 0; j < 2; ++j) bacc[i][j] = (f32x4){0.f,0.f,0.f,0.f};

    #pragma unroll
    for (int ks = 0; ks < 4; ++ks) {
        short8v bfr[2], afr[2];
        #pragma unroll
        for (int fn = 0; fn < 2; ++fn)
            bfr[fn] = *((const short8v*)(Wbt + (size_t)(wid*32 + fn*16 + l15)*IFZ + ks*32 + lg*8));
        #pragma unroll
        for (int fm = 0; fm < 2; ++fm)
            afr[fm] = *((const short8v*)&ctxb[(fm*16 + l15)*68 + ks*16 + lg*4]);
        #pragma unroll
        for (int fm = 0; fm < 2; ++fm)
            #pragma unroll
            for (int fn = 0; fn < 2; ++fn)
                bacc[fm][fn] = __builtin_amdgcn_mfma_f32_16x16x32_bf16(
                    bfr[fn], afr[fm], bacc[fm][fn], 0, 0, 0);   // SWAPPED
    }

    // ys init: ys[r][c] = sqrt2*x + bback (640 float4 items over 256 threads)
    for (int i = tid; i < 640; i += 256) {
        const int r = i >> 5, c4 = (i & 31) * 4;
        const float4 xv  = *(const float4*)(x + base + (size_t)r*IFZ + c4);
        const float4 bb4 = *(const float4*)(bback + c4);
        float* yp = &scys[r*132 + c4];
        yp[0] = SQ2*xv.x + bb4.x; yp[1] = SQ2*xv.y + bb4.y;
        yp[2] = SQ2*xv.z + bb4.z; yp[3] = SQ2*xv.w + bb4.w;
    }
    __syncthreads();

    // ---- Phase 5: add fragments into ys (unique (row,col) ownership).
    #pragma unroll
    for (int fm = 0; fm < 2; ++fm) {
        const int row = fm*16 + l15;
        if (row < KZ) {
            #pragma unroll
            for (int fn = 0; fn < 2; ++fn) {
                const int cb = wid*32 + fn*16 + lg*4;
                float* yp = &scys[row*132 + cb];
                yp[0] += bacc[fm][fn][0]; yp[1] += bacc[fm][fn][1];
                yp[2] += bacc[fm][fn][2]; yp[3] += bacc[fm][fn][3];
            }
        }
    }
    __syncthreads();

    // ---- Phase 6: LN stats, 8 threads per row (20 rows x 8 = 160).
    if (tid < 160) {
        const int row = tid >> 3, t = tid & 7;
        float s1 = 0.f, s2 = 0.f;
        #pragma unroll
        for (int i = 0; i < 16; ++i) {
            const float v = scys[row*132 + t*16 + i];
            s1 += v; s2 += v*v;
        }
        s1 += __shfl_xor(s1, 1); s2 += __shfl_xor(s2, 1);
        s1 += __shfl_xor(s1, 2); s2 += __shfl_xor(s2, 2);
        s1 += __shfl_xor(s1, 4); s2 += __shfl_xor(s2, 4);
        if (t == 0) {
            const float mean = s1 * (1.f/IFZ);
            const float var  = s2 * (1.f/IFZ) - mean*mean;
            st2[row][0] = mean;
            st2[row][1] = rsqrtf(var + 1e-5f);
        }
    }
    __syncthreads();

    // ---- Phase 7: normalize + write f32 out.
    for (int i = tid; i < 640; i += 256) {
        const int r = i >> 5, c4 = (i & 31) * 4;
        const float mean = st2[r][0], rstd = st2[r][1];
        const float4 g4 = *(const float4*)(gamma + c4);
        const float4 b4 = *(const float4*)(beta + c4);
        const float4 yv = *(const float4*)&scys[r*132 + c4];
        float4 o;
        o.x = g4.x*(yv.x - mean)*rstd + b4.x;
        o.y = g4.y*(yv.y - mean)*rstd + b4.y;
        o.z = g4.z*(yv.z - mean)*rstd + b4.z;
        o.w = g4.w*(yv.w - mean)*rstd + b4.w;
        *(float4*)(out + base + (size_t)r*IFZ + c4) = o;
    }
}

// ---------------------------------------------------------------------------
extern "C" void kernel_launch(void* const* d_in, const int* in_sizes, int n_in,
                              void* d_out, int out_size, void* d_ws, size_t ws_size,
                              hipStream_t stream) {
    const float* x     = (const float*)d_in[0];
    const int*   edge  = (const int*)  d_in[1];
    const float* Wq    = (const float*)d_in[2];
    const float* Wk    = (const float*)d_in[3];
    const float* Wv    = (const float*)d_in[4];
    const float* Wb    = (const float*)d_in[5];
    const float* Wg    = (const float*)d_in[6];
    const float* bg    = (const float*)d_in[7];
    const float* Wback = (const float*)d_in[8];
    const float* bback = (const float*)d_in[9];
    const float* gamma = (const float*)d_in[10];
    const float* beta  = (const float*)d_in[11];
    float* out = (float*)d_out;

    const size_t RE = (size_t)ROWS * IFZ;   // 5,242,880 elements
    unsigned short* qb  = (unsigned short*)d_ws;
    unsigned short* kb  = qb + RE;
    unsigned short* gb  = kb + RE;
    unsigned short* xb  = gb + RE;
    unsigned short* Wt  = xb + RE;          // 512*128
    unsigned short* Wbt = Wt + 512*128;     // 128*128
    float*          bbuf= (float*)(Wbt + 128*128);   // ROWS*4 f32
    unsigned char*  kf8 = (unsigned char*)(bbuf + (size_t)ROWS*4);  // ROWS*128 B
    unsigned char*  vf8 = kf8 + RE;                                  // ROWS*128 B
    // total ws use ~53 MB

    setup_kernel<<<3040, 256, 0, stream>>>(x, Wq, Wk, Wv, Wg, Wback, Wb,
                                           xb, Wt, Wbt, bbuf);
    proj_gemm  <<<ROWS/128, 256, 0, stream>>>(xb, Wt, bg, qb, kb, gb, kf8, vf8);
    attn_back_ln<<<NN, 256, 0, stream>>>(qb, kb, gb, bbuf, edge, kf8, vf8,
                                         x, Wbt, bback, gamma, beta, out);
}

// Round 12
// 106.296 us; speedup vs baseline: 1.5196x; 1.0450x over previous
//
#include <hip/hip_runtime.h>
#include <math.h>

#define NN   2048
#define KZ   20
#define IFZ  128
#define AHZ  4
#define AFZ  32
#define ROWS (NN*KZ)           // 40960
#define TWO_KZ (2*KZ)          // 40

typedef __attribute__((ext_vector_type(8))) short short8v;   // 8 bf16 = 4 VGPR
typedef __attribute__((ext_vector_type(4))) float f32x4;     // MFMA acc
typedef __attribute__((ext_vector_type(2))) float f32x2;

__device__ __forceinline__ float blo(unsigned int u) {      // low bf16 of packed pair
    union { unsigned int i; float f; } x; x.i = u << 16; return x.f;
}
__device__ __forceinline__ float bhi(unsigned int u) {      // high bf16 of packed pair
    union { unsigned int i; float f; } x; x.i = u & 0xffff0000u; return x.f;
}
__device__ __forceinline__ unsigned short f2b(float f) {
    union { float f; unsigned int i; } x; x.f = f;
    unsigned int r = x.i + 0x7fffu + ((x.i >> 16) & 1u);
    return (unsigned short)(r >> 16);
}
__device__ __forceinline__ unsigned pack2(float a, float b) {
    return (unsigned)f2b(a) | ((unsigned)f2b(b) << 16);
}

// ---------------------------------------------------------------------------
// setup: wtrans (blocks 0..319) | bproj f32 (320..479). prep_x eliminated —
// proj_gemm converts x on the fly.
// ---------------------------------------------------------------------------
__global__ __launch_bounds__(256) void setup_kernel(
    const float* __restrict__ x,
    const float* __restrict__ Wq, const float* __restrict__ Wk,
    const float* __restrict__ Wv, const float* __restrict__ Wg,
    const float* __restrict__ Wback, const float* __restrict__ Wb,
    unsigned short* __restrict__ Wt, unsigned short* __restrict__ Wbt,
    float* __restrict__ bbuf)
{
    const int b   = blockIdx.x;
    const int tid = threadIdx.x;

    if (b < 320) {                        // ---- wtrans
        const int gid = b * 256 + tid;
        if (gid < 512 * 128) {
            const int n = gid >> 7, k = gid & 127;
            const float* W; int c;
            if      (n < 128) { W = Wq; c = n; }
            else if (n < 256) { W = Wk; c = n - 128; }
            else if (n < 384) { W = Wv; c = n - 256; }
            else              { W = Wg; c = n - 384; }
            Wt[gid] = f2b(W[k * 128 + c]);
        } else {
            const int g2 = gid - 512 * 128;
            const int n = g2 >> 7, k = g2 & 127;
            Wbt[g2] = f2b(Wback[k * 128 + n]);
        }
    } else {                              // ---- bproj (f32 x)
        const int row = (b - 320) * 256 + tid;
        const float4* xv = (const float4*)(x + (size_t)row * IFZ);
        const float4* wv = (const float4*)Wb;
        float4 acc = make_float4(0.f, 0.f, 0.f, 0.f);
        #pragma unroll
        for (int k4 = 0; k4 < 32; ++k4) {
            const float4 xc = xv[k4];
            float4 w;
            w = wv[k4*4+0]; acc.x += xc.x*w.x; acc.y += xc.x*w.y; acc.z += xc.x*w.z; acc.w += xc.x*w.w;
            w = wv[k4*4+1]; acc.x += xc.y*w.x; acc.y += xc.y*w.y; acc.z += xc.y*w.z; acc.w += xc.y*w.w;
            w = wv[k4*4+2]; acc.x += xc.z*w.x; acc.y += xc.z*w.y; acc.z += xc.z*w.z; acc.w += xc.z*w.w;
            w = wv[k4*4+3]; acc.x += xc.w*w.x; acc.y += xc.w*w.y; acc.z += xc.w*w.z; acc.w += xc.w*w.w;
        }
        ((float4*)bbuf)[row] = acc;
    }
}

// ---------------------------------------------------------------------------
// proj_gemm v3: reads f32 x directly, packs A-fragments to bf16 in regs
// (read once, reused for all 4 col-buffers). Swapped MFMA -> C^T frag ->
// packed uint2 stores. cc0->qb; cc1->kb+kf8; cc2->vf8 only; cc3->gb (gated).
// ---------------------------------------------------------------------------
__global__ __launch_bounds__(256) void proj_gemm(
    const float* __restrict__ x, const unsigned short* __restrict__ Wt,
    const float* __restrict__ bg,
    unsigned short* __restrict__ qb, unsigned short* __restrict__ kb,
    unsigned short* __restrict__ gb,
    unsigned char* __restrict__ kf8, unsigned char* __restrict__ vf8)
{
    const int row0 = blockIdx.x * 128;
    const int wid  = threadIdx.x >> 6;
    const int lane = threadIdx.x & 63;
    const int wm = wid >> 1, wn = wid & 1;
    const int l15 = lane & 15, lg = lane >> 4;

    // A fragments once, f32 -> bf16 pack: a[ks][fm]
    short8v a[4][4];
    {
        const float* Af = x + ((size_t)(row0 + wm*64 + l15)) * IFZ + lg*8;
        #pragma unroll
        for (int ks = 0; ks < 4; ++ks)
            #pragma unroll
            for (int fm = 0; fm < 4; ++fm) {
                const float4 u0 = *(const float4*)(Af + (size_t)fm*16*IFZ + ks*32);
                const float4 u1 = *(const float4*)(Af + (size_t)fm*16*IFZ + ks*32 + 4);
                union { short8v s; uint4 u; } cv;
                cv.u.x = pack2(u0.x, u0.y);
                cv.u.y = pack2(u0.z, u0.w);
                cv.u.z = pack2(u1.x, u1.y);
                cv.u.w = pack2(u1.z, u1.w);
                a[ks][fm] = cv.s;
            }
    }

    #pragma unroll
    for (int cc = 0; cc < 4; ++cc) {
        const unsigned short* Bb = Wt + ((size_t)(cc*128 + wn*64 + l15)) * IFZ + lg*8;

        f32x4 acc[4][4];
        #pragma unroll
        for (int i = 0; i < 4; ++i)
            #pragma unroll
            for (int j = 0; j < 4; ++j) acc[i][j] = (f32x4){0.f,0.f,0.f,0.f};

        #pragma unroll
        for (int ks = 0; ks < 4; ++ks) {
            short8v b[4];
            #pragma unroll
            for (int f = 0; f < 4; ++f)
                b[f] = *((const short8v*)(Bb + (size_t)f*16*IFZ + ks*32));
            #pragma unroll
            for (int fm = 0; fm < 4; ++fm)
                #pragma unroll
                for (int fn = 0; fn < 4; ++fn)
                    acc[fm][fn] = __builtin_amdgcn_mfma_f32_16x16x32_bf16(
                        b[fn], a[ks][fm], acc[fm][fn], 0, 0, 0);   // SWAPPED
        }

        const bool gate = (cc == 3);
        unsigned short* ob = (cc == 0) ? qb : (cc == 1) ? kb : (cc == 3) ? gb : (unsigned short*)0;
        unsigned char*  f8 = (cc == 1) ? kf8 : (cc == 2) ? vf8 : (unsigned char*)0;

        #pragma unroll
        for (int fm = 0; fm < 4; ++fm) {
            const int row = row0 + wm*64 + fm*16 + l15;
            #pragma unroll
            for (int fn = 0; fn < 4; ++fn) {
                const int cbase = wn*64 + fn*16 + lg*4;
                float v0 = acc[fm][fn][0], v1 = acc[fm][fn][1];
                float v2 = acc[fm][fn][2], v3 = acc[fm][fn][3];
                if (gate) {
                    const float4 bg4 = *(const float4*)(bg + cbase);
                    v0 = 1.f/(1.f + __expf(-(v0 + bg4.x)));
                    v1 = 1.f/(1.f + __expf(-(v1 + bg4.y)));
                    v2 = 1.f/(1.f + __expf(-(v2 + bg4.z)));
                    v3 = 1.f/(1.f + __expf(-(v3 + bg4.w)));
                }
                if (ob) {
                    uint2 o;
                    o.x = pack2(v0, v1);
                    o.y = pack2(v2, v3);
                    *(uint2*)(ob + (size_t)row * IFZ + cbase) = o;
                }
                if (f8) {
                    int p = __builtin_amdgcn_cvt_pk_fp8_f32(v0, v1, 0, false);
                    p     = __builtin_amdgcn_cvt_pk_fp8_f32(v2, v3, p, true);
                    *(unsigned*)(f8 + (size_t)row*128 + cbase) = (unsigned)p;
                }
            }
        }
    }
}

// ---------------------------------------------------------------------------
// attn_back_ln v2: same structure as R10, but ctxb ALIASES the dead qsu/ksu
// region (zero-fill of rows 20-31 moved into phase 3) -> LDS ~26.5 KB,
// 6 blocks/CU ceiling instead of 4.
// ---------------------------------------------------------------------------
__global__ __launch_bounds__(256) void attn_back_ln(
    const unsigned short* __restrict__ qb, const unsigned short* __restrict__ kb,
    const unsigned short* __restrict__ gb,
    const float* __restrict__ bbuf, const int* __restrict__ edge,
    const unsigned char* __restrict__ kf8, const unsigned char* __restrict__ vf8,
    const float* __restrict__ x, const unsigned short* __restrict__ Wbt,
    const float* __restrict__ bback, const float* __restrict__ gamma,
    const float* __restrict__ beta, float* __restrict__ out)
{
    const int n   = blockIdx.x;
    const int tid = threadIdx.x;

    __shared__ unsigned smemA[KZ*80*2];  // qsu[0..1599] | ksu[1600..3199]; ctxb aliases
    __shared__ float    scys[3280];      // sc (scores) then ys (back+LN), aliased
    __shared__ float    bs[KZ*AHZ];
    __shared__ float    st2[KZ][2];
    __shared__ int      es[KZ];

    unsigned* qsu  = smemA;              // [kk][a][20] packed bf16 pairs
    unsigned* ksu  = smemA + KZ*80;
    unsigned* ctxb = smemA;              // 32*68 uints; valid from phase 3 on

    const size_t base  = (size_t)n * (KZ*IFZ);
    const size_t base2 = base >> 1;              // uint index

    {
        const uint4* qsrc = (const uint4*)(qb + base);
        const uint4* ksrc = (const uint4*)(kb + base);
        for (int i = tid; i < KZ*16; i += 256) {
            const int r = i >> 4, u4 = i & 15;
            const int d = r*80 + (u4 >> 2)*20 + (u4 & 3)*4;
            *(uint4*)&qsu[d] = qsrc[i];
            *(uint4*)&ksu[d] = ksrc[i];
        }
    }
    if (tid < KZ)      es[tid] = edge[n*KZ + tid];
    if (tid < KZ*AHZ)  bs[tid] = bbuf[(size_t)n*(KZ*AHZ) + tid];
    __syncthreads();

    const float rscale = 0.17677669529663687f;  // 1/sqrt(32)

    // ---- Phase 1: thread t<240 owns pair p=t/3 (kk=p>>2, a=p&3), part r3.
    if (tid < 240) {
        const int p  = tid / 3, r3 = tid - p*3;
        const int kk = p >> 2, a = p & 3;

        float qf[32];
        {
            const uint4 q0 = *(const uint4*)&qsu[kk*80 + a*20 + 0];
            const uint4 q1 = *(const uint4*)&qsu[kk*80 + a*20 + 4];
            const uint4 q2 = *(const uint4*)&qsu[kk*80 + a*20 + 8];
            const uint4 q3 = *(const uint4*)&qsu[kk*80 + a*20 + 12];
            unsigned qu_[16] = {q0.x,q0.y,q0.z,q0.w, q1.x,q1.y,q1.z,q1.w,
                                q2.x,q2.y,q2.z,q2.w, q3.x,q3.y,q3.z,q3.w};
            #pragma unroll
            for (int c = 0; c < 16; ++c) { qf[2*c] = blo(qu_[c]); qf[2*c+1] = bhi(qu_[c]); }
        }

        // self keys (bf16 LDS)
        for (int j = r3; j < KZ; j += 3) {
            const int kbse = j*80 + a*20;
            const uint4 k0 = *(const uint4*)&ksu[kbse + 0];
            const uint4 k1 = *(const uint4*)&ksu[kbse + 4];
            const uint4 k2 = *(const uint4*)&ksu[kbse + 8];
            const uint4 k3 = *(const uint4*)&ksu[kbse + 12];
            unsigned ku_[16] = {k0.x,k0.y,k0.z,k0.w, k1.x,k1.y,k1.z,k1.w,
                                k2.x,k2.y,k2.z,k2.w, k3.x,k3.y,k3.z,k3.w};
            float s = 0.f;
            #pragma unroll
            for (int c = 0; c < 16; ++c)
                s += qf[2*c]*blo(ku_[c]) + qf[2*c+1]*bhi(ku_[c]);
            scys[p*41 + j] = s*rscale + bs[j*AHZ + a];
        }

        // neighbor keys (fp8)
        {
            const int e = es[kk];
            for (int jj = r3; jj < KZ; jj += 3) {
                const unsigned char* kp = kf8 + ((size_t)e*KZ + jj)*128 + a*32;
                const uint4 k1 = *(const uint4*)kp;
                const uint4 k2 = *(const uint4*)(kp + 16);
                unsigned ks_[8] = {k1.x, k1.y, k1.z, k1.w, k2.x, k2.y, k2.z, k2.w};
                float s = 0.f;
                #pragma unroll
                for (int u = 0; u < 8; ++u) {
                    const f32x2 lo = __builtin_amdgcn_cvt_pk_f32_fp8(ks_[u], false);
                    const f32x2 hi = __builtin_amdgcn_cvt_pk_f32_fp8(ks_[u], true);
                    s += qf[4*u]*lo.x + qf[4*u+1]*lo.y + qf[4*u+2]*hi.x + qf[4*u+3]*hi.y;
                }
                scys[p*41 + KZ + jj] = s*rscale + bbuf[((size_t)e*KZ + jj)*AHZ + a];
            }
        }
    }
    __syncthreads();

    // ---- Phase 2: softmax over 40 keys, one thread per (kk,a) row.
    if (tid < KZ*AHZ) {
        float* row = &scys[tid*41];
        float m = row[0];
        #pragma unroll
        for (int j = 1; j < TWO_KZ; ++j) m = fmaxf(m, row[j]);
        float ssum = 0.f;
        #pragma unroll
        for (int j = 0; j < TWO_KZ; ++j) { const float e = __expf(row[j]-m); row[j] = e; ssum += e; }
        const float inv = 1.f/ssum;
        #pragma unroll
        for (int j = 0; j < TWO_KZ; ++j) row[j] *= inv;
    }
    __syncthreads();     // qsu/ksu/bs now dead -> ctxb may overwrite

    // ---- Phase 3: ctx + gate -> ctxb (LDS, aliased). Zero rows 20-31 too.
    {
        for (int i = tid; i < 12*68; i += 256) ctxb[20*68 + i] = 0u;

        const int kkg = tid >> 6;
        const int c2  = tid & 63;
        const int a   = c2 >> 4;

        unsigned vs_[KZ];
        {
            const unsigned char* vself = vf8 + (size_t)n*(KZ*128) + c2*2;
            #pragma unroll
            for (int j = 0; j < KZ; ++j)
                vs_[j] = *(const unsigned short*)(vself + j*128);
        }

        const unsigned* gbu = (const unsigned*)gb;

        #pragma unroll
        for (int i = 0; i < 5; ++i) {
            const int kk = kkg*5 + i;
            const float* wrow = &scys[(kk*4 + a)*41];
            float acc0 = 0.f, acc1 = 0.f;
            #pragma unroll
            for (int j = 0; j < KZ; ++j) {
                const f32x2 v2 = __builtin_amdgcn_cvt_pk_f32_fp8(vs_[j], false);
                const float w = wrow[j];
                acc0 += w*v2.x; acc1 += w*v2.y;
            }
            const unsigned char* vnb = vf8 + (size_t)es[kk]*(KZ*128) + c2*2;
            #pragma unroll
            for (int j = 0; j < KZ; ++j) {
                const unsigned u = *(const unsigned short*)(vnb + j*128);
                const f32x2 v2 = __builtin_amdgcn_cvt_pk_f32_fp8(u, false);
                const float w = wrow[KZ + j];
                acc0 += w*v2.x; acc1 += w*v2.y;
            }
            const unsigned gu = gbu[base2 + kk*64 + c2];
            ctxb[kk*68 + c2] = pack2(acc0 * blo(gu), acc1 * bhi(gu));
        }
    }
    __syncthreads();     // ctxb ready; scys (scores) dead -> becomes ys

    // ---- Phase 4: back-GEMM compute (MFMA) + ys init (overlapped).
    const int wid  = tid >> 6;
    const int lane = tid & 63;
    const int l15  = lane & 15, lg = lane >> 4;
    const float SQ2 = 1.4142135623730951f;

    f32x4 bacc[2][2];
    #pragma unroll
    for (int i = 0; i < 2; ++i)
        #pragma unroll
        for (int j = 0; j < 2; ++j) bacc[i][j] = (f32x4){0.f,0.f,0.f,0.f};

    #pragma unroll
    for (int ks = 0; ks < 4; ++ks) {
        short8v bfr[2], afr[2];
        #pragma unroll
        for (int fn = 0; fn < 2; ++fn)
            bfr[fn] = *((const short8v*)(Wbt + (size_t)(wid*32 + fn*16 + l15)*IFZ + ks*32 + lg*8));
        #pragma unroll
        for (int fm = 0; fm < 2; ++fm)
            afr[fm] = *((const short8v*)&ctxb[(fm*16 + l15)*68 + ks*16 + lg*4]);
        #pragma unroll
        for (int fm = 0; fm < 2; ++fm)
            #pragma unroll
            for (int fn = 0; fn < 2; ++fn)
                bacc[fm][fn] = __builtin_amdgcn_mfma_f32_16x16x32_bf16(
                    bfr[fn], afr[fm], bacc[fm][fn], 0, 0, 0);   // SWAPPED
    }

    // ys init: ys[r][c] = sqrt2*x + bback (640 float4 items over 256 threads)
    for (int i = tid; i < 640; i += 256) {
        const int r = i >> 5, c4 = (i & 31) * 4;
        const float4 xv  = *(const float4*)(x + base + (size_t)r*IFZ + c4);
        const float4 bb4 = *(const float4*)(bback + c4);
        float* yp = &scys[r*132 + c4];
        yp[0] = SQ2*xv.x + bb4.x; yp[1] = SQ2*xv.y + bb4.y;
        yp[2] = SQ2*xv.z + bb4.z; yp[3] = SQ2*xv.w + bb4.w;
    }
    __syncthreads();

    // ---- Phase 5: add fragments into ys (unique (row,col) ownership).
    #pragma unroll
    for (int fm = 0; fm < 2; ++fm) {
        const int row = fm*16 + l15;
        if (row < KZ) {
            #pragma unroll
            for (int fn = 0; fn < 2; ++fn) {
                const int cb = wid*32 + fn*16 + lg*4;
                float* yp = &scys[row*132 + cb];
                yp[0] += bacc[fm][fn][0]; yp[1] += bacc[fm][fn][1];
                yp[2] += bacc[fm][fn][2]; yp[3] += bacc[fm][fn][3];
            }
        }
    }
    __syncthreads();

    // ---- Phase 6: LN stats, 8 threads per row (20 rows x 8 = 160).
    if (tid < 160) {
        const int row = tid >> 3, t = tid & 7;
        float s1 = 0.f, s2 = 0.f;
        #pragma unroll
        for (int i = 0; i < 16; ++i) {
            const float v = scys[row*132 + t*16 + i];
            s1 += v; s2 += v*v;
        }
        s1 += __shfl_xor(s1, 1); s2 += __shfl_xor(s2, 1);
        s1 += __shfl_xor(s1, 2); s2 += __shfl_xor(s2, 2);
        s1 += __shfl_xor(s1, 4); s2 += __shfl_xor(s2, 4);
        if (t == 0) {
            const float mean = s1 * (1.f/IFZ);
            const float var  = s2 * (1.f/IFZ) - mean*mean;
            st2[row][0] = mean;
            st2[row][1] = rsqrtf(var + 1e-5f);
        }
    }
    __syncthreads();

    // ---- Phase 7: normalize + write f32 out.
    for (int i = tid; i < 640; i += 256) {
        const int r = i >> 5, c4 = (i & 31) * 4;
        const float mean = st2[r][0], rstd = st2[r][1];
        const float4 g4 = *(const float4*)(gamma + c4);
        const float4 b4 = *(const float4*)(beta + c4);
        const float4 yv = *(const float4*)&scys[r*132 + c4];
        float4 o;
        o.x = g4.x*(yv.x - mean)*rstd + b4.x;
        o.y = g4.y*(yv.y - mean)*rstd + b4.y;
        o.z = g4.z*(yv.z - mean)*rstd + b4.z;
        o.w = g4.w*(yv.w - mean)*rstd + b4.w;
        *(float4*)(out + base + (size_t)r*IFZ + c4) = o;
    }
}

// ---------------------------------------------------------------------------
extern "C" void kernel_launch(void* const* d_in, const int* in_sizes, int n_in,
                              void* d_out, int out_size, void* d_ws, size_t ws_size,
                              hipStream_t stream) {
    const float* x     = (const float*)d_in[0];
    const int*   edge  = (const int*)  d_in[1];
    const float* Wq    = (const float*)d_in[2];
    const float* Wk    = (const float*)d_in[3];
    const float* Wv    = (const float*)d_in[4];
    const float* Wb    = (const float*)d_in[5];
    const float* Wg    = (const float*)d_in[6];
    const float* bg    = (const float*)d_in[7];
    const float* Wback = (const float*)d_in[8];
    const float* bback = (const float*)d_in[9];
    const float* gamma = (const float*)d_in[10];
    const float* beta  = (const float*)d_in[11];
    float* out = (float*)d_out;

    const size_t RE = (size_t)ROWS * IFZ;   // 5,242,880 elements
    unsigned short* qb  = (unsigned short*)d_ws;
    unsigned short* kb  = qb + RE;
    unsigned short* gb  = kb + RE;
    unsigned short* Wt  = gb + RE;          // 512*128
    unsigned short* Wbt = Wt + 512*128;     // 128*128
    float*          bbuf= (float*)(Wbt + 128*128);   // ROWS*4 f32
    unsigned char*  kf8 = (unsigned char*)(bbuf + (size_t)ROWS*4);  // ROWS*128 B
    unsigned char*  vf8 = kf8 + RE;                                  // ROWS*128 B
    // total ws use ~43 MB

    setup_kernel<<<480, 256, 0, stream>>>(x, Wq, Wk, Wv, Wg, Wback, Wb,
                                          Wt, Wbt, bbuf);
    proj_gemm  <<<ROWS/128, 256, 0, stream>>>(x, Wt, bg, qb, kb, gb, kf8, vf8);
    attn_back_ln<<<NN, 256, 0, stream>>>(qb, kb, gb, bbuf, edge, kf8, vf8,
                                         x, Wbt, bback, gamma, beta, out);
}

// Round 13
// 98.456 us; speedup vs baseline: 1.6406x; 1.0796x over previous
//
#include <hip/hip_runtime.h>
#include <math.h>

#define NN   2048
#define KZ   20
#define IFZ  128
#define AHZ  4
#define AFZ  32
#define ROWS (NN*KZ)           // 40960
#define TWO_KZ (2*KZ)          // 40

typedef __attribute__((ext_vector_type(8))) short short8v;   // 8 bf16 = 4 VGPR
typedef __attribute__((ext_vector_type(4))) float f32x4;     // MFMA acc
typedef __attribute__((ext_vector_type(2))) float f32x2;

__device__ __forceinline__ float blo(unsigned int u) {      // low bf16 of packed pair
    union { unsigned int i; float f; } x; x.i = u << 16; return x.f;
}
__device__ __forceinline__ float bhi(unsigned int u) {      // high bf16 of packed pair
    union { unsigned int i; float f; } x; x.i = u & 0xffff0000u; return x.f;
}
__device__ __forceinline__ unsigned short f2b(float f) {
    union { float f; unsigned int i; } x; x.f = f;
    unsigned int r = x.i + 0x7fffu + ((x.i >> 16) & 1u);
    return (unsigned short)(r >> 16);
}
__device__ __forceinline__ unsigned pack2(float a, float b) {
    return (unsigned)f2b(a) | ((unsigned)f2b(b) << 16);
}
__device__ __forceinline__ float dot16(uint4 q, uint4 k) {  // 8 bf16-pair products
    return blo(q.x)*blo(k.x) + bhi(q.x)*bhi(k.x)
         + blo(q.y)*blo(k.y) + bhi(q.y)*bhi(k.y)
         + blo(q.z)*blo(k.z) + bhi(q.z)*bhi(k.z)
         + blo(q.w)*blo(k.w) + bhi(q.w)*bhi(k.w);
}

// ---------------------------------------------------------------------------
// setup: wtrans (blocks 0..319) | bproj f32 (320..479).
// ---------------------------------------------------------------------------
__global__ __launch_bounds__(256) void setup_kernel(
    const float* __restrict__ x,
    const float* __restrict__ Wq, const float* __restrict__ Wk,
    const float* __restrict__ Wv, const float* __restrict__ Wg,
    const float* __restrict__ Wback, const float* __restrict__ Wb,
    unsigned short* __restrict__ Wt, unsigned short* __restrict__ Wbt,
    float* __restrict__ bbuf)
{
    const int b   = blockIdx.x;
    const int tid = threadIdx.x;

    if (b < 320) {                        // ---- wtrans
        const int gid = b * 256 + tid;
        if (gid < 512 * 128) {
            const int n = gid >> 7, k = gid & 127;
            const float* W; int c;
            if      (n < 128) { W = Wq; c = n; }
            else if (n < 256) { W = Wk; c = n - 128; }
            else if (n < 384) { W = Wv; c = n - 256; }
            else              { W = Wg; c = n - 384; }
            Wt[gid] = f2b(W[k * 128 + c]);
        } else {
            const int g2 = gid - 512 * 128;
            const int n = g2 >> 7, k = g2 & 127;
            Wbt[g2] = f2b(Wback[k * 128 + n]);
        }
    } else {                              // ---- bproj (f32 x)
        const int row = (b - 320) * 256 + tid;
        const float4* xv = (const float4*)(x + (size_t)row * IFZ);
        const float4* wv = (const float4*)Wb;
        float4 acc = make_float4(0.f, 0.f, 0.f, 0.f);
        #pragma unroll
        for (int k4 = 0; k4 < 32; ++k4) {
            const float4 xc = xv[k4];
            float4 w;
            w = wv[k4*4+0]; acc.x += xc.x*w.x; acc.y += xc.x*w.y; acc.z += xc.x*w.z; acc.w += xc.x*w.w;
            w = wv[k4*4+1]; acc.x += xc.y*w.x; acc.y += xc.y*w.y; acc.z += xc.y*w.z; acc.w += xc.y*w.w;
            w = wv[k4*4+2]; acc.x += xc.z*w.x; acc.y += xc.z*w.y; acc.z += xc.z*w.z; acc.w += xc.z*w.w;
            w = wv[k4*4+3]; acc.x += xc.w*w.x; acc.y += xc.w*w.y; acc.z += xc.w*w.z; acc.w += xc.w*w.w;
        }
        ((float4*)bbuf)[row] = acc;
    }
}

// ---------------------------------------------------------------------------
// proj_gemm v3: reads f32 x directly, packs A-fragments to bf16 in regs.
// Swapped MFMA -> C^T frag -> packed uint2 stores.
// cc0->qb; cc1->kb+kf8; cc2->vf8 only; cc3->gb (gated).
// ---------------------------------------------------------------------------
__global__ __launch_bounds__(256) void proj_gemm(
    const float* __restrict__ x, const unsigned short* __restrict__ Wt,
    const float* __restrict__ bg,
    unsigned short* __restrict__ qb, unsigned short* __restrict__ kb,
    unsigned short* __restrict__ gb,
    unsigned char* __restrict__ kf8, unsigned char* __restrict__ vf8)
{
    const int row0 = blockIdx.x * 128;
    const int wid  = threadIdx.x >> 6;
    const int lane = threadIdx.x & 63;
    const int wm = wid >> 1, wn = wid & 1;
    const int l15 = lane & 15, lg = lane >> 4;

    short8v a[4][4];
    {
        const float* Af = x + ((size_t)(row0 + wm*64 + l15)) * IFZ + lg*8;
        #pragma unroll
        for (int ks = 0; ks < 4; ++ks)
            #pragma unroll
            for (int fm = 0; fm < 4; ++fm) {
                const float4 u0 = *(const float4*)(Af + (size_t)fm*16*IFZ + ks*32);
                const float4 u1 = *(const float4*)(Af + (size_t)fm*16*IFZ + ks*32 + 4);
                union { short8v s; uint4 u; } cv;
                cv.u.x = pack2(u0.x, u0.y);
                cv.u.y = pack2(u0.z, u0.w);
                cv.u.z = pack2(u1.x, u1.y);
                cv.u.w = pack2(u1.z, u1.w);
                a[ks][fm] = cv.s;
            }
    }

    #pragma unroll
    for (int cc = 0; cc < 4; ++cc) {
        const unsigned short* Bb = Wt + ((size_t)(cc*128 + wn*64 + l15)) * IFZ + lg*8;

        f32x4 acc[4][4];
        #pragma unroll
        for (int i = 0; i < 4; ++i)
            #pragma unroll
            for (int j = 0; j < 4; ++j) acc[i][j] = (f32x4){0.f,0.f,0.f,0.f};

        #pragma unroll
        for (int ks = 0; ks < 4; ++ks) {
            short8v b[4];
            #pragma unroll
            for (int f = 0; f < 4; ++f)
                b[f] = *((const short8v*)(Bb + (size_t)f*16*IFZ + ks*32));
            #pragma unroll
            for (int fm = 0; fm < 4; ++fm)
                #pragma unroll
                for (int fn = 0; fn < 4; ++fn)
                    acc[fm][fn] = __builtin_amdgcn_mfma_f32_16x16x32_bf16(
                        b[fn], a[ks][fm], acc[fm][fn], 0, 0, 0);   // SWAPPED
        }

        const bool gate = (cc == 3);
        unsigned short* ob = (cc == 0) ? qb : (cc == 1) ? kb : (cc == 3) ? gb : (unsigned short*)0;
        unsigned char*  f8 = (cc == 1) ? kf8 : (cc == 2) ? vf8 : (unsigned char*)0;

        #pragma unroll
        for (int fm = 0; fm < 4; ++fm) {
            const int row = row0 + wm*64 + fm*16 + l15;
            #pragma unroll
            for (int fn = 0; fn < 4; ++fn) {
                const int cbase = wn*64 + fn*16 + lg*4;
                float v0 = acc[fm][fn][0], v1 = acc[fm][fn][1];
                float v2 = acc[fm][fn][2], v3 = acc[fm][fn][3];
                if (gate) {
                    const float4 bg4 = *(const float4*)(bg + cbase);
                    v0 = 1.f/(1.f + __expf(-(v0 + bg4.x)));
                    v1 = 1.f/(1.f + __expf(-(v1 + bg4.y)));
                    v2 = 1.f/(1.f + __expf(-(v2 + bg4.z)));
                    v3 = 1.f/(1.f + __expf(-(v3 + bg4.w)));
                }
                if (ob) {
                    uint2 o;
                    o.x = pack2(v0, v1);
                    o.y = pack2(v2, v3);
                    *(uint2*)(ob + (size_t)row * IFZ + cbase) = o;
                }
                if (f8) {
                    int p = __builtin_amdgcn_cvt_pk_fp8_f32(v0, v1, 0, false);
                    p     = __builtin_amdgcn_cvt_pk_fp8_f32(v2, v3, p, true);
                    *(unsigned*)(f8 + (size_t)row*128 + cbase) = (unsigned)p;
                }
            }
        }
    }
}

// ---------------------------------------------------------------------------
// attn_back_ln v3: R8-style transient-register it-loops in phases 1 & 3
// (no qf[32]/vs_[20] hoists -> target VGPR <= 64, 8 waves/SIMD eligible).
// ctxb aliases dead qsu/ksu; scys aliases scores->ys. LDS ~26.5 KB.
// ---------------------------------------------------------------------------
__global__ __launch_bounds__(256) void attn_back_ln(
    const unsigned short* __restrict__ qb, const unsigned short* __restrict__ kb,
    const unsigned short* __restrict__ gb,
    const float* __restrict__ bbuf, const int* __restrict__ edge,
    const unsigned char* __restrict__ kf8, const unsigned char* __restrict__ vf8,
    const float* __restrict__ x, const unsigned short* __restrict__ Wbt,
    const float* __restrict__ bback, const float* __restrict__ gamma,
    const float* __restrict__ beta, float* __restrict__ out)
{
    const int n   = blockIdx.x;
    const int tid = threadIdx.x;

    __shared__ unsigned smemA[KZ*80*2];  // qsu | ksu; ctxb aliases from phase 3
    __shared__ float    scys[3280];      // scores, then ys (aliased)
    __shared__ float    bs[KZ*AHZ];
    __shared__ float    st2[KZ][2];
    __shared__ int      es[KZ];

    unsigned* qsu  = smemA;              // [kk][a][20] packed bf16 pairs
    unsigned* ksu  = smemA + KZ*80;
    unsigned* ctxb = smemA;              // 32*68 uints; valid from phase 3 on

    const size_t base  = (size_t)n * (KZ*IFZ);
    const size_t base2 = base >> 1;              // uint index

    {
        const uint4* qsrc = (const uint4*)(qb + base);
        const uint4* ksrc = (const uint4*)(kb + base);
        for (int i = tid; i < KZ*16; i += 256) {
            const int r = i >> 4, u4 = i & 15;
            const int d = r*80 + (u4 >> 2)*20 + (u4 & 3)*4;
            *(uint4*)&qsu[d] = qsrc[i];
            *(uint4*)&ksu[d] = ksrc[i];
        }
    }
    if (tid < KZ)      es[tid] = edge[n*KZ + tid];
    if (tid < KZ*AHZ)  bs[tid] = bbuf[(size_t)n*(KZ*AHZ) + tid];
    __syncthreads();

    const float rscale = 0.17677669529663687f;  // 1/sqrt(32)

    // ---- Phase 1a: self scores, it-loop, transient regs (1600 items).
    for (int it = tid; it < KZ*KZ*AHZ; it += 256) {
        const int a  = it & 3;
        const int j  = (it >> 2) % KZ;
        const int kk = it / (KZ*AHZ);
        const unsigned* qrow = &qsu[kk*80 + a*20];
        const unsigned* krow = &ksu[j*80 + a*20];
        const uint4 q0 = *(const uint4*)&qrow[0];
        const uint4 q1 = *(const uint4*)&qrow[4];
        const uint4 q2 = *(const uint4*)&qrow[8];
        const uint4 q3 = *(const uint4*)&qrow[12];
        const uint4 k0 = *(const uint4*)&krow[0];
        const uint4 k1 = *(const uint4*)&krow[4];
        const uint4 k2 = *(const uint4*)&krow[8];
        const uint4 k3 = *(const uint4*)&krow[12];
        const float s = dot16(q0,k0) + dot16(q1,k1) + dot16(q2,k2) + dot16(q3,k3);
        scys[(kk*4 + a)*41 + j] = s*rscale + bs[j*AHZ + a];
    }

    // ---- Phase 1b: neighbor scores from kf8, it-loop (1600 items).
    for (int it = tid; it < KZ*KZ*AHZ; it += 256) {
        const int a  = it & 3;
        const int jj = (it >> 2) % KZ;
        const int kk = it / (KZ*AHZ);
        const int e  = es[kk];
        const unsigned* qrow = &qsu[kk*80 + a*20];
        const unsigned char* kp = kf8 + ((size_t)e*KZ + jj)*128 + a*32;
        const uint4 k1 = *(const uint4*)kp;
        const uint4 k2 = *(const uint4*)(kp + 16);
        unsigned ks_[8] = {k1.x, k1.y, k1.z, k1.w, k2.x, k2.y, k2.z, k2.w};
        float s = 0.f;
        #pragma unroll
        for (int u = 0; u < 8; ++u) {
            const f32x2 lo = __builtin_amdgcn_cvt_pk_f32_fp8(ks_[u], false);
            const f32x2 hi = __builtin_amdgcn_cvt_pk_f32_fp8(ks_[u], true);
            const unsigned q0 = qrow[2*u], q1 = qrow[2*u+1];
            s += blo(q0)*lo.x + bhi(q0)*lo.y + blo(q1)*hi.x + bhi(q1)*hi.y;
        }
        scys[(kk*4 + a)*41 + KZ + jj] = s*rscale + bbuf[((size_t)e*KZ + jj)*AHZ + a];
    }
    __syncthreads();

    // ---- Phase 2: softmax over 40 keys, one thread per (kk,a) row.
    if (tid < KZ*AHZ) {
        float* row = &scys[tid*41];
        float m = row[0];
        #pragma unroll
        for (int j = 1; j < TWO_KZ; ++j) m = fmaxf(m, row[j]);
        float ssum = 0.f;
        #pragma unroll
        for (int j = 0; j < TWO_KZ; ++j) { const float e = __expf(row[j]-m); row[j] = e; ssum += e; }
        const float inv = 1.f/ssum;
        #pragma unroll
        for (int j = 0; j < TWO_KZ; ++j) row[j] *= inv;
    }
    __syncthreads();     // qsu/ksu/bs now dead -> ctxb may overwrite

    // ---- Phase 3: ctx + gate -> ctxb (LDS, aliased), it-loop transient.
    {
        for (int i = tid; i < 12*68; i += 256) ctxb[20*68 + i] = 0u;

        const unsigned* gbu = (const unsigned*)gb;
        for (int it = tid; it < KZ*64; it += 256) {
            const int kk = it >> 6;
            const int c2 = it & 63;
            const int a  = c2 >> 4;
            const float* wrow = &scys[(kk*4 + a)*41];
            float acc0 = 0.f, acc1 = 0.f;
            const unsigned char* vself = vf8 + (size_t)n*(KZ*128) + c2*2;
            #pragma unroll
            for (int j = 0; j < KZ; ++j) {
                const unsigned u = *(const unsigned short*)(vself + j*128);
                const f32x2 v2 = __builtin_amdgcn_cvt_pk_f32_fp8(u, false);
                const float w = wrow[j];
                acc0 += w*v2.x; acc1 += w*v2.y;
            }
            const unsigned char* vnb = vf8 + (size_t)es[kk]*(KZ*128) + c2*2;
            #pragma unroll
            for (int j = 0; j < KZ; ++j) {
                const unsigned u = *(const unsigned short*)(vnb + j*128);
                const f32x2 v2 = __builtin_amdgcn_cvt_pk_f32_fp8(u, false);
                const float w = wrow[KZ + j];
                acc0 += w*v2.x; acc1 += w*v2.y;
            }
            const unsigned gu = gbu[base2 + it];
            ctxb[kk*68 + c2] = pack2(acc0 * blo(gu), acc1 * bhi(gu));
        }
    }
    __syncthreads();     // ctxb ready; scys (scores) dead -> becomes ys

    // ---- Phase 4: back-GEMM compute (MFMA) + ys init (overlapped).
    const int wid  = tid >> 6;
    const int lane = tid & 63;
    const int l15  = lane & 15, lg = lane >> 4;
    const float SQ2 = 1.4142135623730951f;

    f32x4 bacc[2][2];
    #pragma unroll
    for (int i = 0; i < 2; ++i)
        #pragma unroll
        for (int j = 0; j < 2; ++j) bacc[i][j] = (f32x4){0.f,0.f,0.f,0.f};

    #pragma unroll
    for (int ks = 0; ks < 4; ++ks) {
        short8v bfr[2], afr[2];
        #pragma unroll
        for (int fn = 0; fn < 2; ++fn)
            bfr[fn] = *((const short8v*)(Wbt + (size_t)(wid*32 + fn*16 + l15)*IFZ + ks*32 + lg*8));
        #pragma unroll
        for (int fm = 0; fm < 2; ++fm)
            afr[fm] = *((const short8v*)&ctxb[(fm*16 + l15)*68 + ks*16 + lg*4]);
        #pragma unroll
        for (int fm = 0; fm < 2; ++fm)
            #pragma unroll
            for (int fn = 0; fn < 2; ++fn)
                bacc[fm][fn] = __builtin_amdgcn_mfma_f32_16x16x32_bf16(
                    bfr[fn], afr[fm], bacc[fm][fn], 0, 0, 0);   // SWAPPED
    }

    // ys init: ys[r][c] = sqrt2*x + bback (640 float4 items over 256 threads)
    for (int i = tid; i < 640; i += 256) {
        const int r = i >> 5, c4 = (i & 31) * 4;
        const float4 xv  = *(const float4*)(x + base + (size_t)r*IFZ + c4);
        const float4 bb4 = *(const float4*)(bback + c4);
        float* yp = &scys[r*132 + c4];
        yp[0] = SQ2*xv.x + bb4.x; yp[1] = SQ2*xv.y + bb4.y;
        yp[2] = SQ2*xv.z + bb4.z; yp[3] = SQ2*xv.w + bb4.w;
    }
    __syncthreads();

    // ---- Phase 5: add fragments into ys (unique (row,col) ownership).
    #pragma unroll
    for (int fm = 0; fm < 2; ++fm) {
        const int row = fm*16 + l15;
        if (row < KZ) {
            #pragma unroll
            for (int fn = 0; fn < 2; ++fn) {
                const int cb = wid*32 + fn*16 + lg*4;
                float* yp = &scys[row*132 + cb];
                yp[0] += bacc[fm][fn][0]; yp[1] += bacc[fm][fn][1];
                yp[2] += bacc[fm][fn][2]; yp[3] += bacc[fm][fn][3];
            }
        }
    }
    __syncthreads();

    // ---- Phase 6: LN stats, 8 threads per row (20 rows x 8 = 160).
    if (tid < 160) {
        const int row = tid >> 3, t = tid & 7;
        float s1 = 0.f, s2 = 0.f;
        #pragma unroll
        for (int i = 0; i < 16; ++i) {
            const float v = scys[row*132 + t*16 + i];
            s1 += v; s2 += v*v;
        }
        s1 += __shfl_xor(s1, 1); s2 += __shfl_xor(s2, 1);
        s1 += __shfl_xor(s1, 2); s2 += __shfl_xor(s2, 2);
        s1 += __shfl_xor(s1, 4); s2 += __shfl_xor(s2, 4);
        if (t == 0) {
            const float mean = s1 * (1.f/IFZ);
            const float var  = s2 * (1.f/IFZ) - mean*mean;
            st2[row][0] = mean;
            st2[row][1] = rsqrtf(var + 1e-5f);
        }
    }
    __syncthreads();

    // ---- Phase 7: normalize + write f32 out.
    for (int i = tid; i < 640; i += 256) {
        const int r = i >> 5, c4 = (i & 31) * 4;
        const float mean = st2[r][0], rstd = st2[r][1];
        const float4 g4 = *(const float4*)(gamma + c4);
        const float4 b4 = *(const float4*)(beta + c4);
        const float4 yv = *(const float4*)&scys[r*132 + c4];
        float4 o;
        o.x = g4.x*(yv.x - mean)*rstd + b4.x;
        o.y = g4.y*(yv.y - mean)*rstd + b4.y;
        o.z = g4.z*(yv.z - mean)*rstd + b4.z;
        o.w = g4.w*(yv.w - mean)*rstd + b4.w;
        *(float4*)(out + base + (size_t)r*IFZ + c4) = o;
    }
}

// ---------------------------------------------------------------------------
extern "C" void kernel_launch(void* const* d_in, const int* in_sizes, int n_in,
                              void* d_out, int out_size, void* d_ws, size_t ws_size,
                              hipStream_t stream) {
    const float* x     = (const float*)d_in[0];
    const int*   edge  = (const int*)  d_in[1];
    const float* Wq    = (const float*)d_in[2];
    const float* Wk    = (const float*)d_in[3];
    const float* Wv    = (const float*)d_in[4];
    const float* Wb    = (const float*)d_in[5];
    const float* Wg    = (const float*)d_in[6];
    const float* bg    = (const float*)d_in[7];
    const float* Wback = (const float*)d_in[8];
    const float* bback = (const float*)d_in[9];
    const float* gamma = (const float*)d_in[10];
    const float* beta  = (const float*)d_in[11];
    float* out = (float*)d_out;

    const size_t RE = (size_t)ROWS * IFZ;   // 5,242,880 elements
    unsigned short* qb  = (unsigned short*)d_ws;
    unsigned short* kb  = qb + RE;
    unsigned short* gb  = kb + RE;
    unsigned short* Wt  = gb + RE;          // 512*128
    unsigned short* Wbt = Wt + 512*128;     // 128*128
    float*          bbuf= (float*)(Wbt + 128*128);   // ROWS*4 f32
    unsigned char*  kf8 = (unsigned char*)(bbuf + (size_t)ROWS*4);  // ROWS*128 B
    unsigned char*  vf8 = kf8 + RE;                                  // ROWS*128 B
    // total ws use ~43 MB

    setup_kernel<<<480, 256, 0, stream>>>(x, Wq, Wk, Wv, Wg, Wback, Wb,
                                          Wt, Wbt, bbuf);
    proj_gemm  <<<ROWS/128, 256, 0, stream>>>(x, Wt, bg, qb, kb, gb, kf8, vf8);
    attn_back_ln<<<NN, 256, 0, stream>>>(qb, kb, gb, bbuf, edge, kf8, vf8,
                                         x, Wbt, bback, gamma, beta, out);
}